// Round 2
// baseline (490.286 us; speedup 1.0000x reference)
//
#include <hip/hip_runtime.h>

#define N_NODES  100000
#define N_EDGES  1600000
#define N_GRAPHS 512
#define HID      128
#define NB       196        // coarse buckets of 512 nodes (dst >> 9)
#define NCHUNK   196        // edge chunks of 8192
#define CHUNK    8192

typedef unsigned int  uint;
typedef unsigned char uchar;
typedef unsigned short ushort;
typedef __attribute__((ext_vector_type(8))) short  short8;   // 8 bf16 (4 VGPRs)
typedef __attribute__((ext_vector_type(4))) float  f32x4;
typedef __attribute__((ext_vector_type(2))) float  f32x2;

__device__ inline float bflo(uint u) { return __uint_as_float(u << 16); }
__device__ inline float bfhi(uint u) { return __uint_as_float(u & 0xffff0000u); }
__device__ inline ushort f2bf(float f) {
    uint u = __float_as_uint(f);
    return (ushort)((u + 0x7fffu + ((u >> 16) & 1u)) >> 16);   // RNE
}
__device__ inline uint pk(float a, float b) {
    return (uint)f2bf(a) | ((uint)f2bf(b) << 16);
}

// unweighted row accumulate (norm folded into stored G = dinv * H)
__device__ inline void acc8_bf16(uint4 hv, float* a) {
    a[0] += bflo(hv.x); a[1] += bfhi(hv.x);
    a[2] += bflo(hv.y); a[3] += bfhi(hv.y);
    a[4] += bflo(hv.z); a[5] += bfhi(hv.z);
    a[6] += bflo(hv.w); a[7] += bfhi(hv.w);
}
__device__ inline void acc8_fp8(uint2 hv, float* a) {
    f32x2 p0 = __builtin_amdgcn_cvt_pk_f32_fp8((int)hv.x, false);
    f32x2 p1 = __builtin_amdgcn_cvt_pk_f32_fp8((int)hv.x, true);
    f32x2 p2 = __builtin_amdgcn_cvt_pk_f32_fp8((int)hv.y, false);
    f32x2 p3 = __builtin_amdgcn_cvt_pk_f32_fp8((int)hv.y, true);
    a[0] += p0.x; a[1] += p0.y; a[2] += p1.x; a[3] += p1.y;
    a[4] += p2.x; a[5] += p2.y; a[6] += p3.x; a[7] += p3.y;
}

// ---------------- prep: pack W | graph boundaries | zero pad rows ----------------
// blocks: [0,224) pack, [224,615) boundary, [615] pads
__global__ __launch_bounds__(256)
void prep_kernel(const float* __restrict__ Wt, const float* __restrict__ W1,
                 const float* __restrict__ Ws, ushort* __restrict__ packed,
                 const int* __restrict__ batch, int* __restrict__ gstart,
                 ushort* __restrict__ xb, uchar* __restrict__ H1f8,
                 ushort* __restrict__ H2) {
    int b = blockIdx.x;
    int t = threadIdx.x;
    if (b < 224) {                          // pack weights into MFMA B-frag order
        int tid = b * 256 + t;
        const float* src; int p; ushort* dst;
        if (tid < 16384)      { src = Wt;         p = tid;         dst = packed; }
        else if (tid < 24576) { src = W1;         p = tid - 16384; dst = packed + 16384; }
        else if (tid < 40960) { src = Ws;         p = tid - 24576; dst = packed + 24576; }
        else                  { src = Ws + 16384; p = tid - 40960; dst = packed + 40960; }
        int j  = p & 7;
        int L  = (p >> 3) & 63;
        int cb = (p >> 9) & 7;
        int s  = p >> 12;
        int k  = s * 32 + (L >> 4) * 8 + j;
        int n  = cb * 16 + (L & 15);
        dst[p] = f2bf(src[k * 128 + n]);
    } else if (b < 615) {                   // graph boundary scan (batch sorted)
        int i = (b - 224) * 256 + t;
        if (i >= N_NODES) return;
        int bb = batch[i];
        int prev = (i == 0) ? -1 : batch[i - 1];
        for (int g = prev + 1; g <= bb; ++g) gstart[g] = i;
        if (i == N_NODES - 1) {
            for (int g = bb + 1; g <= N_GRAPHS; ++g) gstart[g] = N_NODES;
        }
    } else {                                // zero pad row (node N) in each gather buffer
        if (t < 64)  xb[(size_t)N_NODES * 64 + t] = 0;
        if (t < 128) H1f8[(size_t)N_NODES * 128 + t] = 0;
        if (t < 128) H2[(size_t)N_NODES * 128 + t] = 0;
    }
}

// ---------------- CSR build v2: 2-level bucketed counting sort ----------------

// B1: per-chunk coarse histogram (LDS only, no global atomics)
__global__ __launch_bounds__(256)
void hist_chunks(const int* __restrict__ dst, int* __restrict__ chunk_hist) {
    __shared__ int h[NB];
    int c = blockIdx.x, t = threadIdx.x;
    if (t < NB) h[t] = 0;
    __syncthreads();
    const int4* d4 = (const int4*)dst;
#pragma unroll
    for (int k = 0; k < 8; ++k) {
        int i4 = c * (CHUNK / 4) + k * 256 + t;
        if (i4 < N_EDGES / 4) {
            int4 d = d4[i4];
            atomicAdd(&h[d.x >> 9], 1);
            atomicAdd(&h[d.y >> 9], 1);
            atomicAdd(&h[d.z >> 9], 1);
            atomicAdd(&h[d.w >> 9], 1);
        }
    }
    __syncthreads();
    if (t < NB) chunk_hist[c * NB + t] = h[t];
}

// B2: single block — bucket bases + per-(chunk,bucket) bases
__global__ __launch_bounds__(256)
void scan_chunks(const int* __restrict__ chunk_hist, int* __restrict__ cbase,
                 int* __restrict__ bstart, int* __restrict__ row_ptr) {
    __shared__ int sc[256];
    int t = threadIdx.x;
    int tot = 0;
    if (t < NB)
        for (int c = 0; c < NCHUNK; ++c) tot += chunk_hist[c * NB + t];
    sc[t] = (t < NB) ? tot : 0;
    __syncthreads();
    for (int off = 1; off < 256; off <<= 1) {
        int x = (t >= off) ? sc[t - off] : 0;
        __syncthreads();
        sc[t] += x;
        __syncthreads();
    }
    int excl = sc[t] - ((t < NB) ? tot : 0);
    if (t < NB) {
        bstart[t] = excl;
        int run = excl;
        for (int c = 0; c < NCHUNK; ++c) {
            cbase[c * NB + t] = run;
            run += chunk_hist[c * NB + t];
        }
    }
    if (t == 0) { bstart[NB] = N_EDGES; row_ptr[N_NODES] = N_EDGES; }
}

// B3: per-chunk scatter into tmp — block writes contiguous runs per bucket (coalesced)
__global__ __launch_bounds__(256)
void scatter_coarse(const int* __restrict__ src, const int* __restrict__ dst,
                    const int* __restrict__ cbase, uint* __restrict__ tmp) {
    __shared__ int cur[NB];
    int c = blockIdx.x, t = threadIdx.x;
    if (t < NB) cur[t] = cbase[c * NB + t];
    __syncthreads();
    const int4* s4p = (const int4*)src;
    const int4* d4p = (const int4*)dst;
#pragma unroll
    for (int k = 0; k < 8; ++k) {
        int i4 = c * (CHUNK / 4) + k * 256 + t;
        if (i4 < N_EDGES / 4) {
            int4 s = s4p[i4];
            int4 d = d4p[i4];
            int p;
            p = atomicAdd(&cur[d.x >> 9], 1); tmp[p] = (uint)s.x | (((uint)(d.x & 511)) << 17);
            p = atomicAdd(&cur[d.y >> 9], 1); tmp[p] = (uint)s.y | (((uint)(d.y & 511)) << 17);
            p = atomicAdd(&cur[d.z >> 9], 1); tmp[p] = (uint)s.z | (((uint)(d.z & 511)) << 17);
            p = atomicAdd(&cur[d.w >> 9], 1); tmp[p] = (uint)s.w | (((uint)(d.w & 511)) << 17);
        }
    }
}

// C: one block per bucket — local hist+scan -> row_ptr/dinv, fine scatter (XCD-local
// 32KB region -> coalesced writeback), and fused xb = bf16(dinv * x)
__global__ __launch_bounds__(256)
void csr_fine(const uint* __restrict__ tmp, const int* __restrict__ bstart,
              int* __restrict__ row_ptr, float* __restrict__ dinv,
              int* __restrict__ edge, const float* __restrict__ x,
              ushort* __restrict__ xb) {
    __shared__ int   cnt[512];
    __shared__ float dvloc[512];
    __shared__ int   ps[256];
    int b = blockIdx.x, t = threadIdx.x;
    int node0 = b << 9;
    int ncnt = min(512, N_NODES - node0);
    int s = bstart[b], e = bstart[b + 1];
    cnt[t] = 0; cnt[t + 256] = 0;
    __syncthreads();
    for (int i = s + t; i < e; i += 256) atomicAdd(&cnt[tmp[i] >> 17], 1);
    __syncthreads();
    int c0 = cnt[2 * t], c1 = cnt[2 * t + 1];
    int pair = c0 + c1;
    ps[t] = pair;
    __syncthreads();
    for (int off = 1; off < 256; off <<= 1) {
        int v = (t >= off) ? ps[t - off] : 0;
        __syncthreads();
        ps[t] += v;
        __syncthreads();
    }
    int ep = ps[t] - pair;                   // exclusive pair prefix
    int p0 = s + ep, p1 = s + ep + c0;
    float dv0 = rsqrtf((float)(c0 + 1));
    float dv1 = rsqrtf((float)(c1 + 1));
    int n0 = node0 + 2 * t;
    if (2 * t < ncnt)     { row_ptr[n0]     = p0; dinv[n0]     = dv0; }
    if (2 * t + 1 < ncnt) { row_ptr[n0 + 1] = p1; dinv[n0 + 1] = dv1; }
    dvloc[2 * t] = dv0; dvloc[2 * t + 1] = dv1;
    cnt[2 * t] = p0; cnt[2 * t + 1] = p1;    // convert counts -> absolute cursors
    __syncthreads();
    for (int i = s + t; i < e; i += 256) {
        uint rec = tmp[i];
        int p = atomicAdd(&cnt[rec >> 17], 1);
        edge[p] = (int)(rec & 0x1FFFFu);
    }
    // fused: xb rows for this bucket = bf16(dinv * x)
    for (int idx = t; idx < ncnt * 16; idx += 256) {
        int row = idx >> 4, q = idx & 15;
        float4 f = ((const float4*)(x + (size_t)(node0 + row) * 64))[q];
        float d = dvloc[row];
        uint2 o; o.x = pk(f.x * d, f.y * d); o.y = pk(f.z * d, f.w * d);
        *(uint2*)(xb + (size_t)(node0 + row) * 64 + q * 4) = o;
    }
}

// ---------------- fused GCN conv ----------------
// input rows are G = dinv*H; agg_v = dinv_v * (sum_{s in N(v)} G_s + G_v)
// O = relu(agg @ W + b) [+ relu(temb @ Wt + bt)]; SCALEOUT: store dinv*O (next layer's G)
// ROWS=8 per wave-tile: MFMA M=16 half-wasted (MfmaUtil ~2%, free) but grid doubles
// -> 32 resident waves/CU (was 24, grid-limited) for the latency-bound gather.
template <int K, bool TEMB, bool SRC8, bool OUT8, bool SCALEOUT>
__global__ __launch_bounds__(256)
void fused_conv(const void* __restrict__ Hv, const int* __restrict__ rp,
                const int* __restrict__ edge, const float* __restrict__ dinv,
                const ushort* __restrict__ Wp, const float* __restrict__ bias,
                const float* __restrict__ temb, const ushort* __restrict__ Wtp,
                const float* __restrict__ bias_t, void* __restrict__ Ov, int ntiles) {
    constexpr int LPR  = K / 8;       // lanes per gathered row (8 feats/lane)
    constexpr int G    = 64 / LPR;    // edge groups per wave
    constexpr int LROW = 136;         // LDS row stride in shorts (bf16 staging)
    constexpr int ROWS = 8;           // gathered rows per wave-tile
    __shared__ __align__(16) ushort sA[4][16 * LROW];   // 16 rows: epilogue staging
    const int wave = threadIdx.x >> 6;
    const int lane = threadIdx.x & 63;
    const int tile = blockIdx.x * 4 + wave;
    if (tile >= ntiles) return;       // per-wave LDS, no barriers: safe
    const int row0 = tile * ROWS;
    const int g  = lane / LPR;
    const int fq = lane % LPR;
    ushort* myA = sA[wave];
    const ushort* Hb = (const ushort*)Hv;
    const uchar*  H8 = (const uchar*)Hv;

    // hoist row_ptr / dinv off the per-row critical path (lane-parallel, shfl later)
    int   rpv = (lane <= ROWS) ? rp[row0 + lane] : 0;
    float dvv = (lane <  ROWS) ? dinv[row0 + lane] : 0.f;

    // ---- phase 1: gather ROWS rows into LDS (4-deep unrolled edge loop) ----
    for (int r = 0; r < ROWS; ++r) {
        int s = __shfl(rpv, r), e = __shfl(rpv, r + 1);
        int v = row0 + r;
        float a[8] = {0.f, 0.f, 0.f, 0.f, 0.f, 0.f, 0.f, 0.f};
        if (g == 0) {   // self-loop term: + G_v
            if constexpr (!SRC8) {
                uint4 xv = *(const uint4*)(Hb + (size_t)v * K + fq * 8);
                acc8_bf16(xv, a);
            } else {
                uint2 xv = *(const uint2*)(H8 + (size_t)v * K + fq * 8);
                acc8_fp8(xv, a);
            }
        }
        int iters = (e - s + G - 1) / G;   // wave-uniform
        int j = s + g;
        for (int i = 0; i < iters; i += 4, j += 4 * G) {
            int sv[4];
#pragma unroll
            for (int u = 0; u < 4; ++u) {
                int jv = j + u * G;
                int jj = (jv < e) ? jv : e - 1;   // iters>0 => e>s => e-1 valid
                int rec = edge[jj];
                sv[u] = (jv < e) ? rec : N_NODES; // OOB -> zero pad row
            }
            if constexpr (!SRC8) {
                uint4 hv[4];
#pragma unroll
                for (int u = 0; u < 4; ++u)
                    hv[u] = *(const uint4*)(Hb + (size_t)sv[u] * K + fq * 8);
#pragma unroll
                for (int u = 0; u < 4; ++u) acc8_bf16(hv[u], a);
            } else {
                uint2 hv[4];
#pragma unroll
                for (int u = 0; u < 4; ++u)
                    hv[u] = *(const uint2*)(H8 + (size_t)sv[u] * K + fq * 8);
#pragma unroll
                for (int u = 0; u < 4; ++u) acc8_fp8(hv[u], a);
            }
        }
        // reduce across edge groups
        for (int d = LPR; d < 64; d <<= 1) {
#pragma unroll
            for (int k = 0; k < 8; ++k) a[k] += __shfl_xor(a[k], d);
        }
        if (g == 0) {
            float dv = __shfl(dvv, r);        // row-uniform scale
            uint4 o;
            o.x = pk(a[0] * dv, a[1] * dv); o.y = pk(a[2] * dv, a[3] * dv);
            o.z = pk(a[4] * dv, a[5] * dv); o.w = pk(a[6] * dv, a[7] * dv);
            *(uint4*)(myA + r * LROW + fq * 8) = o;
        }
    }

    // ---- phase 2: MFMA (A from LDS, B packed from global/L2) ----
    // A rows 8..15 are stale LDS garbage; C row i depends only on A row i -> safe.
    const int m = lane & 15, q = lane >> 4;
    f32x4 acc[8];
#pragma unroll
    for (int cb = 0; cb < 8; ++cb) acc[cb] = {0.f, 0.f, 0.f, 0.f};
    constexpr int S = K / 32;
#pragma unroll
    for (int s = 0; s < S; ++s) {
        short8 av = *(const short8*)(myA + m * LROW + s * 32 + q * 8);
#pragma unroll
        for (int cb = 0; cb < 8; ++cb) {
            short8 b = *(const short8*)(Wp + (size_t)((s * 8 + cb) * 64 + lane) * 8);
            acc[cb] = __builtin_amdgcn_mfma_f32_16x16x32_bf16(av, b, acc[cb], 0, 0, 0);
        }
    }

    // ---- phase 2b (TEMB): second MFMA chain, A = f32 temb rows cvt'd in-register ----
    f32x4 acc2[TEMB ? 8 : 1];
    if constexpr (TEMB) {
#pragma unroll
        for (int cb = 0; cb < 8; ++cb) acc2[cb] = {0.f, 0.f, 0.f, 0.f};
        int trow = row0 + m;
        if (trow > N_NODES - 1) trow = N_NODES - 1;   // rows >= ROWS unused
        const float* Arow = temb + (size_t)trow * 128 + q * 8;
#pragma unroll
        for (int s2 = 0; s2 < 4; ++s2) {
            float4 f0 = *(const float4*)(Arow + s2 * 32);
            float4 f1 = *(const float4*)(Arow + s2 * 32 + 4);
            uint4 uu;
            uu.x = pk(f0.x, f0.y); uu.y = pk(f0.z, f0.w);
            uu.z = pk(f1.x, f1.y); uu.w = pk(f1.z, f1.w);
            short8 av = *(short8*)&uu;
#pragma unroll
            for (int cb = 0; cb < 8; ++cb) {
                short8 b = *(const short8*)(Wtp + (size_t)((s2 * 8 + cb) * 64 + lane) * 8);
                acc2[cb] = __builtin_amdgcn_mfma_f32_16x16x32_bf16(av, b, acc2[cb], 0, 0, 0);
            }
        }
    }

    // ---- phase 3: epilogue into LDS, coalesced store (ROWS rows only) ----
    // C/D layout: col = lane&15, row = (lane>>4)*4 + r
    float dsc[4];
    if constexpr (SCALEOUT) {
#pragma unroll
        for (int r = 0; r < 4; ++r) {
            int rr = q * 4 + r;
            dsc[r] = (rr < ROWS) ? __shfl(dvv, rr) : 0.f;
        }
    }
    if constexpr (!OUT8) {
        ushort* Ob = (ushort*)Ov;
#pragma unroll
        for (int cb = 0; cb < 8; ++cb) {
            int colc = cb * 16 + m;
            float bv = bias[colc];
            float bt2 = TEMB ? bias_t[colc] : 0.f;
#pragma unroll
            for (int r = 0; r < 4; ++r) {
                int row = q * 4 + r;
                float v = fmaxf(acc[cb][r] + bv, 0.0f);
                if (TEMB) v += fmaxf(acc2[cb][r] + bt2, 0.0f);
                if (SCALEOUT) v *= dsc[r];
                myA[row * LROW + colc] = f2bf(v);
            }
        }
#pragma unroll
        for (int i = 0; i < 2; ++i) {          // 8 rows out
            int srow = i * 4 + (lane >> 4);
            int scol = (lane & 15) * 8;
            *(short8*)(Ob + (size_t)(row0 + srow) * 128 + scol) =
                *(const short8*)(myA + srow * LROW + scol);
        }
    } else {
        uchar* st8 = (uchar*)myA;           // byte staging, row stride 136 B
        uchar* Ob = (uchar*)Ov;
#pragma unroll
        for (int cb = 0; cb < 8; ++cb) {
            int colc = cb * 16 + m;
            float bv = bias[colc];
            float bt2 = TEMB ? bias_t[colc] : 0.f;
#pragma unroll
            for (int r = 0; r < 4; ++r) {
                int row = q * 4 + r;
                float v = fmaxf(acc[cb][r] + bv, 0.0f);
                if (TEMB) v += fmaxf(acc2[cb][r] + bt2, 0.0f);
                if (SCALEOUT) v *= dsc[r];
                int enc = __builtin_amdgcn_cvt_pk_fp8_f32(v, v, 0, false);
                st8[row * 136 + colc] = (uchar)(enc & 0xff);
            }
        }
        // 8 rows * 128 B = 1024 B; 64 lanes * 8 B = 512 B/iter -> 2 iters
#pragma unroll
        for (int i = 0; i < 2; ++i) {
            int idx = i * 64 + lane;        // [0,128)
            int srow = idx >> 4;            // [0,8)
            int soff = (idx & 15) * 8;      // [0,128) step 8
            *(uint2*)(Ob + (size_t)(row0 + srow) * 128 + soff) =
                *(const uint2*)(st8 + srow * 136 + soff);
        }
    }
}

// ---------------- pooling + output head (fused) ----------------

__global__ void pool_out(const ushort* __restrict__ h, const int* __restrict__ gstart,
                         const float* __restrict__ Wo, const float* __restrict__ bo,
                         float* __restrict__ out) {
    int g = blockIdx.x;
    int t = threadIdx.x;          // 256
    int f2 = t & 63;
    int half = t >> 6;
    int s = gstart[g], e = gstart[g + 1];
    float ax = 0.f, ay = 0.f;
    for (int i = s + half; i < e; i += 4) {
        uint u = *(const uint*)(h + (size_t)i * HID + f2 * 2);
        ax += bflo(u); ay += bfhi(u);
    }
    __shared__ float red[2][256];
    __shared__ float P[128];
    red[0][t] = ax; red[1][t] = ay;
    __syncthreads();
    if (half == 0) {
        for (int k = 1; k < 4; ++k) { ax += red[0][f2 + 64 * k]; ay += red[1][f2 + 64 * k]; }
        float c = (float)((e - s) < 1 ? 1 : (e - s));
        P[f2 * 2]     = ax / c;
        P[f2 * 2 + 1] = ay / c;
    }
    __syncthreads();
    if (t < 16) {
        float acc = bo[t];
        for (int k = 0; k < HID; ++k) acc += P[k] * Wo[k * 16 + t];
        out[g * 16 + t] = acc;
    }
}

// ---------------- launch ----------------

extern "C" void kernel_launch(void* const* d_in, const int* in_sizes, int n_in,
                              void* d_out, int out_size, void* d_ws, size_t ws_size,
                              hipStream_t stream) {
    const float* x       = (const float*)d_in[0];
    const int*   ei      = (const int*)d_in[1];
    const float* temb_in = (const float*)d_in[2];
    const int*   batch   = (const int*)d_in[3];
    const float* Wt      = (const float*)d_in[4];
    const float* bt      = (const float*)d_in[5];
    const float* W1      = (const float*)d_in[6];
    const float* b1      = (const float*)d_in[7];
    const float* Ws      = (const float*)d_in[8];
    const float* bs      = (const float*)d_in[9];
    const float* Wo      = (const float*)d_in[10];
    const float* bo      = (const float*)d_in[11];
    float* out = (float*)d_out;

    const int N = N_NODES, E = N_EDGES;
    const int* src = ei;
    const int* dst = ei + E;

    char* p = (char*)d_ws;
    auto carve = [&](size_t bytes) -> void* {
        void* r = (void*)p;
        p += (bytes + 255) & ~(size_t)255;
        return r;
    };
    int*    row_ptr    = (int*)carve((size_t)(N + 1) * 4);
    float*  dinv       = (float*)carve((size_t)N * 4);
    int*    gstart     = (int*)carve((size_t)(N_GRAPHS + 1) * 4);
    ushort* packed     = (ushort*)carve((size_t)57344 * 2);
    int*    chunk_hist = (int*)carve((size_t)NCHUNK * NB * 4);
    int*    cbase      = (int*)carve((size_t)NCHUNK * NB * 4);
    int*    bstart     = (int*)carve((size_t)(NB + 1) * 4);
    uint*   tmp        = (uint*)carve((size_t)E * 4);
    int*    edge       = (int*)carve((size_t)E * 4);
    ushort* xb         = (ushort*)carve((size_t)(N + 16) * 64 * 2);
    uchar*  H1f8       = (uchar*)carve((size_t)(N + 16) * 128);
    ushort* H2         = (ushort*)carve((size_t)(N + 16) * 128 * 2);
    ushort* H3         = (ushort*)carve((size_t)N * 128 * 2);

    const ushort* Wtp  = packed;
    const ushort* W1p  = packed + 16384;
    const ushort* Ws0p = packed + 24576;
    const ushort* Ws1p = packed + 40960;

    const int ntiles = N / 8;             // 12500 (8-row wave-tiles)
    const int gblk   = (ntiles + 3) / 4;  // 3125

    // prep: pack W | boundaries | zero pad rows
    prep_kernel<<<616, 256, 0, stream>>>(Wt, W1, Ws, packed, batch, gstart,
                                         xb, H1f8, H2);

    // CSR build v2 (bucketed counting sort; no global atomics, coalesced writes)
    hist_chunks<<<NCHUNK, 256, 0, stream>>>(dst, chunk_hist);
    scan_chunks<<<1, 256, 0, stream>>>(chunk_hist, cbase, bstart, row_ptr);
    scatter_coarse<<<NCHUNK, 256, 0, stream>>>(src, dst, cbase, tmp);
    csr_fine<<<NB, 256, 0, stream>>>(tmp, bstart, row_ptr, dinv, edge, x, xb);

    // conv1 (+fused temb layer): H1f8 = dinv * (relu(agg(G0)@W1+b1) + relu(temb@Wt+bt))
    fused_conv<64, true, false, true, true><<<gblk, 256, 0, stream>>>(
        xb, row_ptr, edge, dinv, W1p, b1, temb_in, Wtp, bt, H1f8, ntiles);
    // conv2 (fp8 gather): H2 = dinv * relu(agg(H1f8)@Ws0 + bs0)
    fused_conv<128, false, true, false, true><<<gblk, 256, 0, stream>>>(
        H1f8, row_ptr, edge, dinv, Ws0p, bs, nullptr, nullptr, nullptr, H2, ntiles);
    // conv3 (no out-scale, pool consumes raw H): H3 = relu(agg(H2)@Ws1 + bs1)
    fused_conv<128, false, false, false, false><<<gblk, 256, 0, stream>>>(
        H2, row_ptr, edge, dinv, Ws1p, bs + 128, nullptr, nullptr, nullptr, H3, ntiles);

    // pool + head (fused)
    pool_out<<<N_GRAPHS, 256, 0, stream>>>(H3, gstart, Wo, bo, out);
}

// Round 3
// 474.536 us; speedup vs baseline: 1.0332x; 1.0332x over previous
//
#include <hip/hip_runtime.h>

#define N_NODES  100000
#define N_EDGES  1600000
#define N_GRAPHS 512
#define HID      128
#define NB       196        // coarse buckets of 512 nodes (dst >> 9)
#define NCHUNK   196        // edge chunks of 8192
#define CHUNK    8192

typedef unsigned int  uint;
typedef unsigned char uchar;
typedef unsigned short ushort;
typedef __attribute__((ext_vector_type(8))) short  short8;   // 8 bf16 (4 VGPRs)
typedef __attribute__((ext_vector_type(4))) float  f32x4;
typedef __attribute__((ext_vector_type(2))) float  f32x2;

__device__ inline float bflo(uint u) { return __uint_as_float(u << 16); }
__device__ inline float bfhi(uint u) { return __uint_as_float(u & 0xffff0000u); }
__device__ inline ushort f2bf(float f) {
    uint u = __float_as_uint(f);
    return (ushort)((u + 0x7fffu + ((u >> 16) & 1u)) >> 16);   // RNE
}
__device__ inline uint pk(float a, float b) {
    return (uint)f2bf(a) | ((uint)f2bf(b) << 16);
}

// weighted row accumulate; w in {0,1} masks OOB slots (norm folded into G = dinv*H)
__device__ inline void acc8_bf16(uint4 hv, float w, float* a) {
    a[0] += w * bflo(hv.x); a[1] += w * bfhi(hv.x);
    a[2] += w * bflo(hv.y); a[3] += w * bfhi(hv.y);
    a[4] += w * bflo(hv.z); a[5] += w * bfhi(hv.z);
    a[6] += w * bflo(hv.w); a[7] += w * bfhi(hv.w);
}
__device__ inline void acc8_fp8(uint2 hv, float w, float* a) {
    f32x2 p0 = __builtin_amdgcn_cvt_pk_f32_fp8((int)hv.x, false);
    f32x2 p1 = __builtin_amdgcn_cvt_pk_f32_fp8((int)hv.x, true);
    f32x2 p2 = __builtin_amdgcn_cvt_pk_f32_fp8((int)hv.y, false);
    f32x2 p3 = __builtin_amdgcn_cvt_pk_f32_fp8((int)hv.y, true);
    a[0] += w * p0.x; a[1] += w * p0.y; a[2] += w * p1.x; a[3] += w * p1.y;
    a[4] += w * p2.x; a[5] += w * p2.y; a[6] += w * p3.x; a[7] += w * p3.y;
}

// ---------------- prep: pack W | graph boundaries ----------------
// blocks: [0,224) pack, [224,615) boundary
__global__ __launch_bounds__(256)
void prep_kernel(const float* __restrict__ Wt, const float* __restrict__ W1,
                 const float* __restrict__ Ws, ushort* __restrict__ packed,
                 const int* __restrict__ batch, int* __restrict__ gstart) {
    int b = blockIdx.x;
    int t = threadIdx.x;
    if (b < 224) {                          // pack weights into MFMA B-frag order
        int tid = b * 256 + t;
        const float* src; int p; ushort* dst;
        if (tid < 16384)      { src = Wt;         p = tid;         dst = packed; }
        else if (tid < 24576) { src = W1;         p = tid - 16384; dst = packed + 16384; }
        else if (tid < 40960) { src = Ws;         p = tid - 24576; dst = packed + 24576; }
        else                  { src = Ws + 16384; p = tid - 40960; dst = packed + 40960; }
        int j  = p & 7;
        int L  = (p >> 3) & 63;
        int cb = (p >> 9) & 7;
        int s  = p >> 12;
        int k  = s * 32 + (L >> 4) * 8 + j;
        int n  = cb * 16 + (L & 15);
        dst[p] = f2bf(src[k * 128 + n]);
    } else {                                // graph boundary scan (batch sorted)
        int i = (b - 224) * 256 + t;
        if (i >= N_NODES) return;
        int bb = batch[i];
        int prev = (i == 0) ? -1 : batch[i - 1];
        for (int g = prev + 1; g <= bb; ++g) gstart[g] = i;
        if (i == N_NODES - 1) {
            for (int g = bb + 1; g <= N_GRAPHS; ++g) gstart[g] = N_NODES;
        }
    }
}

// ---------------- CSR build v2: 2-level bucketed counting sort ----------------

// B1: per-chunk coarse histogram (LDS only, no global atomics)
__global__ __launch_bounds__(256)
void hist_chunks(const int* __restrict__ dst, int* __restrict__ chunk_hist) {
    __shared__ int h[NB];
    int c = blockIdx.x, t = threadIdx.x;
    if (t < NB) h[t] = 0;
    __syncthreads();
    const int4* d4 = (const int4*)dst;
#pragma unroll
    for (int k = 0; k < 8; ++k) {
        int i4 = c * (CHUNK / 4) + k * 256 + t;
        if (i4 < N_EDGES / 4) {
            int4 d = d4[i4];
            atomicAdd(&h[d.x >> 9], 1);
            atomicAdd(&h[d.y >> 9], 1);
            atomicAdd(&h[d.z >> 9], 1);
            atomicAdd(&h[d.w >> 9], 1);
        }
    }
    __syncthreads();
    if (t < NB) chunk_hist[c * NB + t] = h[t];
}

// B2: single block — bucket bases + per-(chunk,bucket) bases
__global__ __launch_bounds__(256)
void scan_chunks(const int* __restrict__ chunk_hist, int* __restrict__ cbase,
                 int* __restrict__ bstart, int* __restrict__ row_ptr) {
    __shared__ int sc[256];
    int t = threadIdx.x;
    int tot = 0;
    if (t < NB)
        for (int c = 0; c < NCHUNK; ++c) tot += chunk_hist[c * NB + t];
    sc[t] = (t < NB) ? tot : 0;
    __syncthreads();
    for (int off = 1; off < 256; off <<= 1) {
        int x = (t >= off) ? sc[t - off] : 0;
        __syncthreads();
        sc[t] += x;
        __syncthreads();
    }
    int excl = sc[t] - ((t < NB) ? tot : 0);
    if (t < NB) {
        bstart[t] = excl;
        int run = excl;
        for (int c = 0; c < NCHUNK; ++c) {
            cbase[c * NB + t] = run;
            run += chunk_hist[c * NB + t];
        }
    }
    if (t == 0) { bstart[NB] = N_EDGES; row_ptr[N_NODES] = N_EDGES; }
}

// B3: per-chunk scatter into tmp — block writes contiguous runs per bucket (coalesced)
__global__ __launch_bounds__(256)
void scatter_coarse(const int* __restrict__ src, const int* __restrict__ dst,
                    const int* __restrict__ cbase, uint* __restrict__ tmp) {
    __shared__ int cur[NB];
    int c = blockIdx.x, t = threadIdx.x;
    if (t < NB) cur[t] = cbase[c * NB + t];
    __syncthreads();
    const int4* s4p = (const int4*)src;
    const int4* d4p = (const int4*)dst;
#pragma unroll
    for (int k = 0; k < 8; ++k) {
        int i4 = c * (CHUNK / 4) + k * 256 + t;
        if (i4 < N_EDGES / 4) {
            int4 s = s4p[i4];
            int4 d = d4p[i4];
            int p;
            p = atomicAdd(&cur[d.x >> 9], 1); tmp[p] = (uint)s.x | (((uint)(d.x & 511)) << 17);
            p = atomicAdd(&cur[d.y >> 9], 1); tmp[p] = (uint)s.y | (((uint)(d.y & 511)) << 17);
            p = atomicAdd(&cur[d.z >> 9], 1); tmp[p] = (uint)s.z | (((uint)(d.z & 511)) << 17);
            p = atomicAdd(&cur[d.w >> 9], 1); tmp[p] = (uint)s.w | (((uint)(d.w & 511)) << 17);
        }
    }
}

// C: one block per bucket — local hist+scan -> row_ptr/dinv, fine scatter (XCD-local
// 32KB region -> coalesced writeback), and fused xb = bf16(dinv * x)
__global__ __launch_bounds__(256)
void csr_fine(const uint* __restrict__ tmp, const int* __restrict__ bstart,
              int* __restrict__ row_ptr, float* __restrict__ dinv,
              int* __restrict__ edge, const float* __restrict__ x,
              ushort* __restrict__ xb) {
    __shared__ int   cnt[512];
    __shared__ float dvloc[512];
    __shared__ int   ps[256];
    int b = blockIdx.x, t = threadIdx.x;
    int node0 = b << 9;
    int ncnt = min(512, N_NODES - node0);
    int s = bstart[b], e = bstart[b + 1];
    cnt[t] = 0; cnt[t + 256] = 0;
    __syncthreads();
    for (int i = s + t; i < e; i += 256) atomicAdd(&cnt[tmp[i] >> 17], 1);
    __syncthreads();
    int c0 = cnt[2 * t], c1 = cnt[2 * t + 1];
    int pair = c0 + c1;
    ps[t] = pair;
    __syncthreads();
    for (int off = 1; off < 256; off <<= 1) {
        int v = (t >= off) ? ps[t - off] : 0;
        __syncthreads();
        ps[t] += v;
        __syncthreads();
    }
    int ep = ps[t] - pair;                   // exclusive pair prefix
    int p0 = s + ep, p1 = s + ep + c0;
    float dv0 = rsqrtf((float)(c0 + 1));
    float dv1 = rsqrtf((float)(c1 + 1));
    int n0 = node0 + 2 * t;
    if (2 * t < ncnt)     { row_ptr[n0]     = p0; dinv[n0]     = dv0; }
    if (2 * t + 1 < ncnt) { row_ptr[n0 + 1] = p1; dinv[n0 + 1] = dv1; }
    dvloc[2 * t] = dv0; dvloc[2 * t + 1] = dv1;
    cnt[2 * t] = p0; cnt[2 * t + 1] = p1;    // convert counts -> absolute cursors
    __syncthreads();
    for (int i = s + t; i < e; i += 256) {
        uint rec = tmp[i];
        int p = atomicAdd(&cnt[rec >> 17], 1);
        edge[p] = (int)(rec & 0x1FFFFu);
    }
    // fused: xb rows for this bucket = bf16(dinv * x)
    for (int idx = t; idx < ncnt * 16; idx += 256) {
        int row = idx >> 4, q = idx & 15;
        float4 f = ((const float4*)(x + (size_t)(node0 + row) * 64))[q];
        float d = dvloc[row];
        uint2 o; o.x = pk(f.x * d, f.y * d); o.y = pk(f.z * d, f.w * d);
        *(uint2*)(xb + (size_t)(node0 + row) * 64 + q * 4) = o;
    }
}

// ---------------- fused GCN conv ----------------
// input rows are G = dinv*H; agg_v = dinv_v * (sum_{s in N(v)} G_s + G_v)
// O = relu(agg @ W + b) [+ relu(temb @ Wt + bt)]; SCALEOUT: store dinv*O (next layer's G)
// OOB edge slots load the CLAMPED edge's row (well-distributed, L1/L2-warm) and mask
// the accumulate with w=0 — NOT a shared pad row (single-line chip-wide hotspot, R1 bug:
// ~690K loads/conv hammered one L2 bank, convs 85 -> 114 us).
template <int K, bool TEMB, bool SRC8, bool OUT8, bool SCALEOUT>
__global__ __launch_bounds__(256)
void fused_conv(const void* __restrict__ Hv, const int* __restrict__ rp,
                const int* __restrict__ edge, const float* __restrict__ dinv,
                const ushort* __restrict__ Wp, const float* __restrict__ bias,
                const float* __restrict__ temb, const ushort* __restrict__ Wtp,
                const float* __restrict__ bias_t, void* __restrict__ Ov, int ntiles) {
    constexpr int LPR  = K / 8;       // lanes per gathered row (8 feats/lane)
    constexpr int G    = 64 / LPR;    // edge groups per wave
    constexpr int LROW = 136;         // LDS row stride in shorts (bf16 staging)
    __shared__ __align__(16) ushort sA[4][16 * LROW];
    const int wave = threadIdx.x >> 6;
    const int lane = threadIdx.x & 63;
    const int tile = blockIdx.x * 4 + wave;
    if (tile >= ntiles) return;       // per-wave LDS, no barriers: safe
    const int row0 = tile * 16;
    const int g  = lane / LPR;
    const int fq = lane % LPR;
    ushort* myA = sA[wave];
    const ushort* Hb = (const ushort*)Hv;
    const uchar*  H8 = (const uchar*)Hv;

    // ---- phase 1: gather 16 rows into LDS (4-deep unrolled edge loop) ----
    for (int r = 0; r < 16; ++r) {
        int v = row0 + r;
        int s = rp[v], e = rp[v + 1];
        float a[8] = {0.f, 0.f, 0.f, 0.f, 0.f, 0.f, 0.f, 0.f};
        if (g == 0) {   // self-loop term: + G_v
            if constexpr (!SRC8) {
                uint4 xv = *(const uint4*)(Hb + (size_t)v * K + fq * 8);
                acc8_bf16(xv, 1.0f, a);
            } else {
                uint2 xv = *(const uint2*)(H8 + (size_t)v * K + fq * 8);
                acc8_fp8(xv, 1.0f, a);
            }
        }
        int iters = (e - s + G - 1) / G;   // wave-uniform
        int j = s + g;
        for (int i = 0; i < iters; i += 4, j += 4 * G) {
            int sv[4]; float wv[4];
#pragma unroll
            for (int u = 0; u < 4; ++u) {
                int jv = j + u * G;
                int jj = (jv < e) ? jv : e - 1;   // iters>0 => e>s => e-1 valid
                sv[u] = edge[jj];                 // clamped: recent, distributed row
                wv[u] = (jv < e) ? 1.0f : 0.0f;
            }
            if constexpr (!SRC8) {
                uint4 hv[4];
#pragma unroll
                for (int u = 0; u < 4; ++u)
                    hv[u] = *(const uint4*)(Hb + (size_t)sv[u] * K + fq * 8);
#pragma unroll
                for (int u = 0; u < 4; ++u) acc8_bf16(hv[u], wv[u], a);
            } else {
                uint2 hv[4];
#pragma unroll
                for (int u = 0; u < 4; ++u)
                    hv[u] = *(const uint2*)(H8 + (size_t)sv[u] * K + fq * 8);
#pragma unroll
                for (int u = 0; u < 4; ++u) acc8_fp8(hv[u], wv[u], a);
            }
        }
        // reduce across edge groups
        for (int d = LPR; d < 64; d <<= 1) {
#pragma unroll
            for (int k = 0; k < 8; ++k) a[k] += __shfl_xor(a[k], d);
        }
        if (g == 0) {
            float dv = dinv[v];               // row-uniform scale
            uint4 o;
            o.x = pk(a[0] * dv, a[1] * dv); o.y = pk(a[2] * dv, a[3] * dv);
            o.z = pk(a[4] * dv, a[5] * dv); o.w = pk(a[6] * dv, a[7] * dv);
            *(uint4*)(myA + r * LROW + fq * 8) = o;
        }
    }

    // ---- phase 2: MFMA (A from LDS, B packed from global/L2) ----
    const int m = lane & 15, q = lane >> 4;
    f32x4 acc[8];
#pragma unroll
    for (int cb = 0; cb < 8; ++cb) acc[cb] = {0.f, 0.f, 0.f, 0.f};
    constexpr int S = K / 32;
#pragma unroll
    for (int s = 0; s < S; ++s) {
        short8 av = *(const short8*)(myA + m * LROW + s * 32 + q * 8);
#pragma unroll
        for (int cb = 0; cb < 8; ++cb) {
            short8 b = *(const short8*)(Wp + (size_t)((s * 8 + cb) * 64 + lane) * 8);
            acc[cb] = __builtin_amdgcn_mfma_f32_16x16x32_bf16(av, b, acc[cb], 0, 0, 0);
        }
    }

    // ---- phase 2b (TEMB): second MFMA chain, A = f32 temb rows cvt'd in-register ----
    f32x4 acc2[TEMB ? 8 : 1];
    if constexpr (TEMB) {
#pragma unroll
        for (int cb = 0; cb < 8; ++cb) acc2[cb] = {0.f, 0.f, 0.f, 0.f};
        const float* Arow = temb + (size_t)(row0 + m) * 128 + q * 8;
#pragma unroll
        for (int s2 = 0; s2 < 4; ++s2) {
            float4 f0 = *(const float4*)(Arow + s2 * 32);
            float4 f1 = *(const float4*)(Arow + s2 * 32 + 4);
            uint4 uu;
            uu.x = pk(f0.x, f0.y); uu.y = pk(f0.z, f0.w);
            uu.z = pk(f1.x, f1.y); uu.w = pk(f1.z, f1.w);
            short8 av = *(short8*)&uu;
#pragma unroll
            for (int cb = 0; cb < 8; ++cb) {
                short8 b = *(const short8*)(Wtp + (size_t)((s2 * 8 + cb) * 64 + lane) * 8);
                acc2[cb] = __builtin_amdgcn_mfma_f32_16x16x32_bf16(av, b, acc2[cb], 0, 0, 0);
            }
        }
    }

    // ---- phase 3: epilogue into LDS, coalesced store ----
    // C/D layout: col = lane&15, row = (lane>>4)*4 + r
    float dsc[4];
    if constexpr (SCALEOUT) {
#pragma unroll
        for (int r = 0; r < 4; ++r) dsc[r] = dinv[row0 + q * 4 + r];
    }
    if constexpr (!OUT8) {
        ushort* Ob = (ushort*)Ov;
#pragma unroll
        for (int cb = 0; cb < 8; ++cb) {
            int colc = cb * 16 + m;
            float bv = bias[colc];
            float bt2 = TEMB ? bias_t[colc] : 0.f;
#pragma unroll
            for (int r = 0; r < 4; ++r) {
                int row = q * 4 + r;
                float v = fmaxf(acc[cb][r] + bv, 0.0f);
                if (TEMB) v += fmaxf(acc2[cb][r] + bt2, 0.0f);
                if (SCALEOUT) v *= dsc[r];
                myA[row * LROW + colc] = f2bf(v);
            }
        }
#pragma unroll
        for (int i = 0; i < 4; ++i) {
            int srow = i * 4 + (lane >> 4);
            int scol = (lane & 15) * 8;
            *(short8*)(Ob + (size_t)(row0 + srow) * 128 + scol) =
                *(const short8*)(myA + srow * LROW + scol);
        }
    } else {
        uchar* st8 = (uchar*)myA;           // byte staging, row stride 136 B
        uchar* Ob = (uchar*)Ov;
#pragma unroll
        for (int cb = 0; cb < 8; ++cb) {
            int colc = cb * 16 + m;
            float bv = bias[colc];
            float bt2 = TEMB ? bias_t[colc] : 0.f;
#pragma unroll
            for (int r = 0; r < 4; ++r) {
                int row = q * 4 + r;
                float v = fmaxf(acc[cb][r] + bv, 0.0f);
                if (TEMB) v += fmaxf(acc2[cb][r] + bt2, 0.0f);
                if (SCALEOUT) v *= dsc[r];
                int enc = __builtin_amdgcn_cvt_pk_fp8_f32(v, v, 0, false);
                st8[row * 136 + colc] = (uchar)(enc & 0xff);
            }
        }
        // 16 rows * 128 B = 2048 B; 64 lanes * 8 B = 512 B/iter -> 4 iters
#pragma unroll
        for (int i = 0; i < 4; ++i) {
            int idx = i * 64 + lane;        // [0,256)
            int srow = idx >> 4;            // [0,16)
            int soff = (idx & 15) * 8;      // [0,128) step 8
            *(uint2*)(Ob + (size_t)(row0 + srow) * 128 + soff) =
                *(const uint2*)(st8 + srow * 136 + soff);
        }
    }
}

// ---------------- pooling + output head (fused) ----------------

__global__ void pool_out(const ushort* __restrict__ h, const int* __restrict__ gstart,
                         const float* __restrict__ Wo, const float* __restrict__ bo,
                         float* __restrict__ out) {
    int g = blockIdx.x;
    int t = threadIdx.x;          // 256
    int f2 = t & 63;
    int half = t >> 6;
    int s = gstart[g], e = gstart[g + 1];
    float ax = 0.f, ay = 0.f;
    for (int i = s + half; i < e; i += 4) {
        uint u = *(const uint*)(h + (size_t)i * HID + f2 * 2);
        ax += bflo(u); ay += bfhi(u);
    }
    __shared__ float red[2][256];
    __shared__ float P[128];
    red[0][t] = ax; red[1][t] = ay;
    __syncthreads();
    if (half == 0) {
        for (int k = 1; k < 4; ++k) { ax += red[0][f2 + 64 * k]; ay += red[1][f2 + 64 * k]; }
        float c = (float)((e - s) < 1 ? 1 : (e - s));
        P[f2 * 2]     = ax / c;
        P[f2 * 2 + 1] = ay / c;
    }
    __syncthreads();
    if (t < 16) {
        float acc = bo[t];
        for (int k = 0; k < HID; ++k) acc += P[k] * Wo[k * 16 + t];
        out[g * 16 + t] = acc;
    }
}

// ---------------- launch ----------------

extern "C" void kernel_launch(void* const* d_in, const int* in_sizes, int n_in,
                              void* d_out, int out_size, void* d_ws, size_t ws_size,
                              hipStream_t stream) {
    const float* x       = (const float*)d_in[0];
    const int*   ei      = (const int*)d_in[1];
    const float* temb_in = (const float*)d_in[2];
    const int*   batch   = (const int*)d_in[3];
    const float* Wt      = (const float*)d_in[4];
    const float* bt      = (const float*)d_in[5];
    const float* W1      = (const float*)d_in[6];
    const float* b1      = (const float*)d_in[7];
    const float* Ws      = (const float*)d_in[8];
    const float* bs      = (const float*)d_in[9];
    const float* Wo      = (const float*)d_in[10];
    const float* bo      = (const float*)d_in[11];
    float* out = (float*)d_out;

    const int N = N_NODES, E = N_EDGES;
    const int* src = ei;
    const int* dst = ei + E;

    char* p = (char*)d_ws;
    auto carve = [&](size_t bytes) -> void* {
        void* r = (void*)p;
        p += (bytes + 255) & ~(size_t)255;
        return r;
    };
    int*    row_ptr    = (int*)carve((size_t)(N + 1) * 4);
    float*  dinv       = (float*)carve((size_t)N * 4);
    int*    gstart     = (int*)carve((size_t)(N_GRAPHS + 1) * 4);
    ushort* packed     = (ushort*)carve((size_t)57344 * 2);
    int*    chunk_hist = (int*)carve((size_t)NCHUNK * NB * 4);
    int*    cbase      = (int*)carve((size_t)NCHUNK * NB * 4);
    int*    bstart     = (int*)carve((size_t)(NB + 1) * 4);
    uint*   tmp        = (uint*)carve((size_t)E * 4);
    int*    edge       = (int*)carve((size_t)E * 4);
    ushort* xb         = (ushort*)carve((size_t)(N + 16) * 64 * 2);
    uchar*  H1f8       = (uchar*)carve((size_t)(N + 16) * 128);
    ushort* H2         = (ushort*)carve((size_t)(N + 16) * 128 * 2);
    ushort* H3         = (ushort*)carve((size_t)N * 128 * 2);

    const ushort* Wtp  = packed;
    const ushort* W1p  = packed + 16384;
    const ushort* Ws0p = packed + 24576;
    const ushort* Ws1p = packed + 40960;

    const int ntiles = N / 16;            // 6250
    const int gblk   = (ntiles + 3) / 4;  // 1563

    // prep: pack W | boundaries
    prep_kernel<<<615, 256, 0, stream>>>(Wt, W1, Ws, packed, batch, gstart);

    // CSR build v2 (bucketed counting sort; no global atomics, coalesced writes)
    hist_chunks<<<NCHUNK, 256, 0, stream>>>(dst, chunk_hist);
    scan_chunks<<<1, 256, 0, stream>>>(chunk_hist, cbase, bstart, row_ptr);
    scatter_coarse<<<NCHUNK, 256, 0, stream>>>(src, dst, cbase, tmp);
    csr_fine<<<NB, 256, 0, stream>>>(tmp, bstart, row_ptr, dinv, edge, x, xb);

    // conv1 (+fused temb layer): H1f8 = dinv * (relu(agg(G0)@W1+b1) + relu(temb@Wt+bt))
    fused_conv<64, true, false, true, true><<<gblk, 256, 0, stream>>>(
        xb, row_ptr, edge, dinv, W1p, b1, temb_in, Wtp, bt, H1f8, ntiles);
    // conv2 (fp8 gather): H2 = dinv * relu(agg(H1f8)@Ws0 + bs0)
    fused_conv<128, false, true, false, true><<<gblk, 256, 0, stream>>>(
        H1f8, row_ptr, edge, dinv, Ws0p, bs, nullptr, nullptr, nullptr, H2, ntiles);
    // conv3 (no out-scale, pool consumes raw H): H3 = relu(agg(H2)@Ws1 + bs1)
    fused_conv<128, false, false, false, false><<<gblk, 256, 0, stream>>>(
        H2, row_ptr, edge, dinv, Ws1p, bs + 128, nullptr, nullptr, nullptr, H3, ntiles);

    // pool + head (fused)
    pool_out<<<N_GRAPHS, 256, 0, stream>>>(H3, gstart, Wo, bo, out);
}

// Round 4
// 393.160 us; speedup vs baseline: 1.2470x; 1.2070x over previous
//
#include <hip/hip_runtime.h>

#define N_NODES  100000
#define N_EDGES  1600000
#define N_GRAPHS 512
#define HID      128
#define NB       196        // coarse buckets of 512 nodes (dst >> 9)
#define NCHUNK   196        // edge chunks of 8192
#define CHUNK    8192

typedef unsigned int  uint;
typedef unsigned char uchar;
typedef unsigned short ushort;
typedef __attribute__((ext_vector_type(8))) short  short8;   // 8 bf16 (4 VGPRs)
typedef __attribute__((ext_vector_type(4))) float  f32x4;
typedef __attribute__((ext_vector_type(2))) float  f32x2;

__device__ inline float bflo(uint u) { return __uint_as_float(u << 16); }
__device__ inline float bfhi(uint u) { return __uint_as_float(u & 0xffff0000u); }
__device__ inline ushort f2bf(float f) {
    uint u = __float_as_uint(f);
    return (ushort)((u + 0x7fffu + ((u >> 16) & 1u)) >> 16);   // RNE
}
__device__ inline uint pk(float a, float b) {
    return (uint)f2bf(a) | ((uint)f2bf(b) << 16);
}

// weighted row accumulate; w in {0,1} masks OOB slots (norm folded into G = dinv*H)
__device__ inline void acc8_bf16(uint4 hv, float w, float* a) {
    a[0] += w * bflo(hv.x); a[1] += w * bfhi(hv.x);
    a[2] += w * bflo(hv.y); a[3] += w * bfhi(hv.y);
    a[4] += w * bflo(hv.z); a[5] += w * bfhi(hv.z);
    a[6] += w * bflo(hv.w); a[7] += w * bfhi(hv.w);
}
__device__ inline void acc8_fp8(uint2 hv, float w, float* a) {
    f32x2 p0 = __builtin_amdgcn_cvt_pk_f32_fp8((int)hv.x, false);
    f32x2 p1 = __builtin_amdgcn_cvt_pk_f32_fp8((int)hv.x, true);
    f32x2 p2 = __builtin_amdgcn_cvt_pk_f32_fp8((int)hv.y, false);
    f32x2 p3 = __builtin_amdgcn_cvt_pk_f32_fp8((int)hv.y, true);
    a[0] += w * p0.x; a[1] += w * p0.y; a[2] += w * p1.x; a[3] += w * p1.y;
    a[4] += w * p2.x; a[5] += w * p2.y; a[6] += w * p3.x; a[7] += w * p3.y;
}

// ---------------- prep: pack W | graph boundaries | cvt temb -> bf16 ----------------
// blocks: [0,224) pack, [224,615) boundary, [615,3740) temb cvt
__global__ __launch_bounds__(256)
void prep_kernel(const float* __restrict__ Wt, const float* __restrict__ W1,
                 const float* __restrict__ Ws, ushort* __restrict__ packed,
                 const int* __restrict__ batch, int* __restrict__ gstart,
                 const float* __restrict__ temb, ushort* __restrict__ tembb) {
    int b = blockIdx.x;
    int t = threadIdx.x;
    if (b < 224) {                          // pack weights into MFMA B-frag order
        int tid = b * 256 + t;
        const float* src; int p; ushort* dst;
        if (tid < 16384)      { src = Wt;         p = tid;         dst = packed; }
        else if (tid < 24576) { src = W1;         p = tid - 16384; dst = packed + 16384; }
        else if (tid < 40960) { src = Ws;         p = tid - 24576; dst = packed + 24576; }
        else                  { src = Ws + 16384; p = tid - 40960; dst = packed + 40960; }
        int j  = p & 7;
        int L  = (p >> 3) & 63;
        int cb = (p >> 9) & 7;
        int s  = p >> 12;
        int k  = s * 32 + (L >> 4) * 8 + j;
        int n  = cb * 16 + (L & 15);
        dst[p] = f2bf(src[k * 128 + n]);
    } else if (b < 615) {                   // graph boundary scan (batch sorted)
        int i = (b - 224) * 256 + t;
        if (i >= N_NODES) return;
        int bb = batch[i];
        int prev = (i == 0) ? -1 : batch[i - 1];
        for (int g = prev + 1; g <= bb; ++g) gstart[g] = i;
        if (i == N_NODES - 1) {
            for (int g = bb + 1; g <= N_GRAPHS; ++g) gstart[g] = N_NODES;
        }
    } else {                                // cvt temb (N*128 floats, 16/thread, exact)
        long i = ((long)(b - 615) * 256 + t) * 16;
#pragma unroll
        for (int k = 0; k < 4; ++k) {
            float4 f = *(const float4*)(temb + i + k * 4);
            uint2 o; o.x = pk(f.x, f.y); o.y = pk(f.z, f.w);
            *(uint2*)(tembb + i + k * 4) = o;
        }
    }
}

// ---------------- CSR build v2: 2-level bucketed counting sort ----------------

// B1: per-chunk coarse histogram (LDS only, no global atomics)
__global__ __launch_bounds__(256)
void hist_chunks(const int* __restrict__ dst, int* __restrict__ chunk_hist) {
    __shared__ int h[NB];
    int c = blockIdx.x, t = threadIdx.x;
    if (t < NB) h[t] = 0;
    __syncthreads();
    const int4* d4 = (const int4*)dst;
#pragma unroll
    for (int k = 0; k < 8; ++k) {
        int i4 = c * (CHUNK / 4) + k * 256 + t;
        if (i4 < N_EDGES / 4) {
            int4 d = d4[i4];
            atomicAdd(&h[d.x >> 9], 1);
            atomicAdd(&h[d.y >> 9], 1);
            atomicAdd(&h[d.z >> 9], 1);
            atomicAdd(&h[d.w >> 9], 1);
        }
    }
    __syncthreads();
    if (t < NB) chunk_hist[c * NB + t] = h[t];
}

// B2: single block — bucket bases + per-(chunk,bucket) bases
__global__ __launch_bounds__(256)
void scan_chunks(const int* __restrict__ chunk_hist, int* __restrict__ cbase,
                 int* __restrict__ bstart, int* __restrict__ row_ptr) {
    __shared__ int sc[256];
    int t = threadIdx.x;
    int tot = 0;
    if (t < NB)
        for (int c = 0; c < NCHUNK; ++c) tot += chunk_hist[c * NB + t];
    sc[t] = (t < NB) ? tot : 0;
    __syncthreads();
    for (int off = 1; off < 256; off <<= 1) {
        int x = (t >= off) ? sc[t - off] : 0;
        __syncthreads();
        sc[t] += x;
        __syncthreads();
    }
    int excl = sc[t] - ((t < NB) ? tot : 0);
    if (t < NB) {
        bstart[t] = excl;
        int run = excl;
        for (int c = 0; c < NCHUNK; ++c) {
            cbase[c * NB + t] = run;
            run += chunk_hist[c * NB + t];
        }
    }
    if (t == 0) { bstart[NB] = N_EDGES; row_ptr[N_NODES] = N_EDGES; }
}

// B3: per-chunk scatter into tmp — block writes contiguous runs per bucket (coalesced)
__global__ __launch_bounds__(256)
void scatter_coarse(const int* __restrict__ src, const int* __restrict__ dst,
                    const int* __restrict__ cbase, uint* __restrict__ tmp) {
    __shared__ int cur[NB];
    int c = blockIdx.x, t = threadIdx.x;
    if (t < NB) cur[t] = cbase[c * NB + t];
    __syncthreads();
    const int4* s4p = (const int4*)src;
    const int4* d4p = (const int4*)dst;
#pragma unroll
    for (int k = 0; k < 8; ++k) {
        int i4 = c * (CHUNK / 4) + k * 256 + t;
        if (i4 < N_EDGES / 4) {
            int4 s = s4p[i4];
            int4 d = d4p[i4];
            int p;
            p = atomicAdd(&cur[d.x >> 9], 1); tmp[p] = (uint)s.x | (((uint)(d.x & 511)) << 17);
            p = atomicAdd(&cur[d.y >> 9], 1); tmp[p] = (uint)s.y | (((uint)(d.y & 511)) << 17);
            p = atomicAdd(&cur[d.z >> 9], 1); tmp[p] = (uint)s.z | (((uint)(d.z & 511)) << 17);
            p = atomicAdd(&cur[d.w >> 9], 1); tmp[p] = (uint)s.w | (((uint)(d.w & 511)) << 17);
        }
    }
}

// C: one block per bucket — local hist+scan -> row_ptr/dinv, fine scatter (XCD-local
// 32KB region -> coalesced writeback), and fused xb = bf16(dinv * x)
__global__ __launch_bounds__(256)
void csr_fine(const uint* __restrict__ tmp, const int* __restrict__ bstart,
              int* __restrict__ row_ptr, float* __restrict__ dinv,
              int* __restrict__ edge, const float* __restrict__ x,
              ushort* __restrict__ xb) {
    __shared__ int   cnt[512];
    __shared__ float dvloc[512];
    __shared__ int   ps[256];
    int b = blockIdx.x, t = threadIdx.x;
    int node0 = b << 9;
    int ncnt = min(512, N_NODES - node0);
    int s = bstart[b], e = bstart[b + 1];
    cnt[t] = 0; cnt[t + 256] = 0;
    __syncthreads();
    for (int i = s + t; i < e; i += 256) atomicAdd(&cnt[tmp[i] >> 17], 1);
    __syncthreads();
    int c0 = cnt[2 * t], c1 = cnt[2 * t + 1];
    int pair = c0 + c1;
    ps[t] = pair;
    __syncthreads();
    for (int off = 1; off < 256; off <<= 1) {
        int v = (t >= off) ? ps[t - off] : 0;
        __syncthreads();
        ps[t] += v;
        __syncthreads();
    }
    int ep = ps[t] - pair;                   // exclusive pair prefix
    int p0 = s + ep, p1 = s + ep + c0;
    float dv0 = rsqrtf((float)(c0 + 1));
    float dv1 = rsqrtf((float)(c1 + 1));
    int n0 = node0 + 2 * t;
    if (2 * t < ncnt)     { row_ptr[n0]     = p0; dinv[n0]     = dv0; }
    if (2 * t + 1 < ncnt) { row_ptr[n0 + 1] = p1; dinv[n0 + 1] = dv1; }
    dvloc[2 * t] = dv0; dvloc[2 * t + 1] = dv1;
    cnt[2 * t] = p0; cnt[2 * t + 1] = p1;    // convert counts -> absolute cursors
    __syncthreads();
    for (int i = s + t; i < e; i += 256) {
        uint rec = tmp[i];
        int p = atomicAdd(&cnt[rec >> 17], 1);
        edge[p] = (int)(rec & 0x1FFFFu);
    }
    // fused: xb rows for this bucket = bf16(dinv * x)
    for (int idx = t; idx < ncnt * 16; idx += 256) {
        int row = idx >> 4, q = idx & 15;
        float4 f = ((const float4*)(x + (size_t)(node0 + row) * 64))[q];
        float d = dvloc[row];
        uint2 o; o.x = pk(f.x * d, f.y * d); o.y = pk(f.z * d, f.w * d);
        *(uint2*)(xb + (size_t)(node0 + row) * 64 + q * 4) = o;
    }
}

// ---------------- fused GCN conv ----------------
// input rows are G = dinv*H; agg_v = dinv_v * (sum_{s in N(v)} G_s + G_v)
// O = relu(agg @ W + b) [+ relu(tembb @ Wt + bt)]; SCALEOUT: store dinv*O (next layer's G)
// Phase-1 structure: ONE LANE-GROUP PER ROW (G groups of LPR lanes, 16/G serial rows
// each). Kills the 16-deep serial row chain + cross-group shuffle reduce that made
// the conv latency-bound (R3: VALUBusy 31%, HBM 14%, Mfma 2% -> nothing saturated).
template <int K, bool TEMB, bool SRC8, bool OUT8, bool SCALEOUT>
__global__ __launch_bounds__(256)
void fused_conv(const void* __restrict__ Hv, const int* __restrict__ rp,
                const int* __restrict__ edge, const float* __restrict__ dinv,
                const ushort* __restrict__ Wp, const float* __restrict__ bias,
                const ushort* __restrict__ tembb, const ushort* __restrict__ Wtp,
                const float* __restrict__ bias_t, void* __restrict__ Ov, int ntiles) {
    constexpr int LPR  = K / 8;       // lanes per row (8 feats/lane)
    constexpr int G    = 64 / LPR;    // concurrent rows (lane groups)
    constexpr int RPG  = 16 / G;      // serial rows per group
    constexpr int LROW = 136;         // LDS row stride in shorts (bf16 staging)
    __shared__ __align__(16) ushort sA[4][16 * LROW];
    const int wave = threadIdx.x >> 6;
    const int lane = threadIdx.x & 63;
    const int tile = blockIdx.x * 4 + wave;
    if (tile >= ntiles) return;       // per-wave LDS, no barriers: safe
    const int row0 = tile * 16;
    const int g  = lane / LPR;
    const int fq = lane % LPR;
    ushort* myA = sA[wave];
    const ushort* Hb = (const ushort*)Hv;
    const uchar*  H8 = (const uchar*)Hv;

    // lane-parallel preload of row_ptr[17] / dinv[16]; broadcast via shfl
    int   rpv = rp[row0 + ((lane < 17) ? lane : 16)];
    float dvv = dinv[row0 + ((lane < 16) ? lane : 15)];

    // ---- phase 1: each group gathers its own RPG rows (no cross-group reduce) ----
    for (int rr = 0; rr < RPG; ++rr) {
        int r = g * RPG + rr;
        int v = row0 + r;
        int s = __shfl(rpv, r), e = __shfl(rpv, r + 1);
        float a[8];
        // self-loop init: a = G_v
        if constexpr (!SRC8) {
            uint4 xv = *(const uint4*)(Hb + (size_t)v * K + fq * 8);
            a[0] = bflo(xv.x); a[1] = bfhi(xv.x);
            a[2] = bflo(xv.y); a[3] = bfhi(xv.y);
            a[4] = bflo(xv.z); a[5] = bfhi(xv.z);
            a[6] = bflo(xv.w); a[7] = bfhi(xv.w);
        } else {
            uint2 xv = *(const uint2*)(H8 + (size_t)v * K + fq * 8);
            f32x2 p0 = __builtin_amdgcn_cvt_pk_f32_fp8((int)xv.x, false);
            f32x2 p1 = __builtin_amdgcn_cvt_pk_f32_fp8((int)xv.x, true);
            f32x2 p2 = __builtin_amdgcn_cvt_pk_f32_fp8((int)xv.y, false);
            f32x2 p3 = __builtin_amdgcn_cvt_pk_f32_fp8((int)xv.y, true);
            a[0] = p0.x; a[1] = p0.y; a[2] = p1.x; a[3] = p1.y;
            a[4] = p2.x; a[5] = p2.y; a[6] = p3.x; a[7] = p3.y;
        }
        int iters = (e - s + 3) >> 2;     // group-uniform; 4-deep unrolled walk
        int j = s;
        for (int i = 0; i < iters; ++i, j += 4) {
            int sv[4]; float wv[4];
#pragma unroll
            for (int u = 0; u < 4; ++u) {
                int jv = j + u;
                int jj = (jv < e) ? jv : e - 1;   // iters>0 => e>s => e-1 valid
                sv[u] = edge[jj];                 // clamped: recent, distributed row
                wv[u] = (jv < e) ? 1.0f : 0.0f;
            }
            if constexpr (!SRC8) {
                uint4 hv[4];
#pragma unroll
                for (int u = 0; u < 4; ++u)
                    hv[u] = *(const uint4*)(Hb + (size_t)sv[u] * K + fq * 8);
#pragma unroll
                for (int u = 0; u < 4; ++u) acc8_bf16(hv[u], wv[u], a);
            } else {
                uint2 hv[4];
#pragma unroll
                for (int u = 0; u < 4; ++u)
                    hv[u] = *(const uint2*)(H8 + (size_t)sv[u] * K + fq * 8);
#pragma unroll
                for (int u = 0; u < 4; ++u) acc8_fp8(hv[u], wv[u], a);
            }
        }
        float dv = __shfl(dvv, r);        // row-uniform scale
        uint4 o;
        o.x = pk(a[0] * dv, a[1] * dv); o.y = pk(a[2] * dv, a[3] * dv);
        o.z = pk(a[4] * dv, a[5] * dv); o.w = pk(a[6] * dv, a[7] * dv);
        *(uint4*)(myA + r * LROW + fq * 8) = o;
    }

    // ---- phase 2: MFMA (A from LDS, B packed from global/L2) ----
    const int m = lane & 15, q = lane >> 4;
    f32x4 acc[8];
#pragma unroll
    for (int cb = 0; cb < 8; ++cb) acc[cb] = {0.f, 0.f, 0.f, 0.f};
    constexpr int S = K / 32;
#pragma unroll
    for (int s = 0; s < S; ++s) {
        short8 av = *(const short8*)(myA + m * LROW + s * 32 + q * 8);
#pragma unroll
        for (int cb = 0; cb < 8; ++cb) {
            short8 b = *(const short8*)(Wp + (size_t)((s * 8 + cb) * 64 + lane) * 8);
            acc[cb] = __builtin_amdgcn_mfma_f32_16x16x32_bf16(av, b, acc[cb], 0, 0, 0);
        }
    }

    // ---- phase 2b (TEMB): second MFMA chain, A = prepacked bf16 temb rows ----
    f32x4 acc2[TEMB ? 8 : 1];
    if constexpr (TEMB) {
#pragma unroll
        for (int cb = 0; cb < 8; ++cb) acc2[cb] = {0.f, 0.f, 0.f, 0.f};
        const ushort* Arow = tembb + (size_t)(row0 + m) * 128 + q * 8;
#pragma unroll
        for (int s2 = 0; s2 < 4; ++s2) {
            short8 av = *(const short8*)(Arow + s2 * 32);
#pragma unroll
            for (int cb = 0; cb < 8; ++cb) {
                short8 b = *(const short8*)(Wtp + (size_t)((s2 * 8 + cb) * 64 + lane) * 8);
                acc2[cb] = __builtin_amdgcn_mfma_f32_16x16x32_bf16(av, b, acc2[cb], 0, 0, 0);
            }
        }
    }

    // ---- phase 3: epilogue into LDS, coalesced store ----
    // C/D layout: col = lane&15, row = (lane>>4)*4 + r
    float dsc[4];
    if constexpr (SCALEOUT) {
#pragma unroll
        for (int r = 0; r < 4; ++r) dsc[r] = __shfl(dvv, q * 4 + r);
    }
    if constexpr (!OUT8) {
        ushort* Ob = (ushort*)Ov;
#pragma unroll
        for (int cb = 0; cb < 8; ++cb) {
            int colc = cb * 16 + m;
            float bv = bias[colc];
            float bt2 = TEMB ? bias_t[colc] : 0.f;
#pragma unroll
            for (int r = 0; r < 4; ++r) {
                int row = q * 4 + r;
                float v = fmaxf(acc[cb][r] + bv, 0.0f);
                if (TEMB) v += fmaxf(acc2[cb][r] + bt2, 0.0f);
                if (SCALEOUT) v *= dsc[r];
                myA[row * LROW + colc] = f2bf(v);
            }
        }
#pragma unroll
        for (int i = 0; i < 4; ++i) {
            int srow = i * 4 + (lane >> 4);
            int scol = (lane & 15) * 8;
            *(short8*)(Ob + (size_t)(row0 + srow) * 128 + scol) =
                *(const short8*)(myA + srow * LROW + scol);
        }
    } else {
        uchar* st8 = (uchar*)myA;           // byte staging, row stride 136 B
        uchar* Ob = (uchar*)Ov;
#pragma unroll
        for (int cb = 0; cb < 8; ++cb) {
            int colc = cb * 16 + m;
            float bv = bias[colc];
            float bt2 = TEMB ? bias_t[colc] : 0.f;
#pragma unroll
            for (int r = 0; r < 4; ++r) {
                int row = q * 4 + r;
                float v = fmaxf(acc[cb][r] + bv, 0.0f);
                if (TEMB) v += fmaxf(acc2[cb][r] + bt2, 0.0f);
                if (SCALEOUT) v *= dsc[r];
                int enc = __builtin_amdgcn_cvt_pk_fp8_f32(v, v, 0, false);
                st8[row * 136 + colc] = (uchar)(enc & 0xff);
            }
        }
        // 16 rows * 128 B = 2048 B; 64 lanes * 8 B = 512 B/iter -> 4 iters
#pragma unroll
        for (int i = 0; i < 4; ++i) {
            int idx = i * 64 + lane;        // [0,256)
            int srow = idx >> 4;            // [0,16)
            int soff = (idx & 15) * 8;      // [0,128) step 8
            *(uint2*)(Ob + (size_t)(row0 + srow) * 128 + soff) =
                *(const uint2*)(st8 + srow * 136 + soff);
        }
    }
}

// ---------------- pooling + output head (fused) ----------------

__global__ void pool_out(const ushort* __restrict__ h, const int* __restrict__ gstart,
                         const float* __restrict__ Wo, const float* __restrict__ bo,
                         float* __restrict__ out) {
    int g = blockIdx.x;
    int t = threadIdx.x;          // 256
    int f2 = t & 63;
    int half = t >> 6;
    int s = gstart[g], e = gstart[g + 1];
    float ax = 0.f, ay = 0.f;
    for (int i = s + half; i < e; i += 4) {
        uint u = *(const uint*)(h + (size_t)i * HID + f2 * 2);
        ax += bflo(u); ay += bfhi(u);
    }
    __shared__ float red[2][256];
    __shared__ float P[128];
    red[0][t] = ax; red[1][t] = ay;
    __syncthreads();
    if (half == 0) {
        for (int k = 1; k < 4; ++k) { ax += red[0][f2 + 64 * k]; ay += red[1][f2 + 64 * k]; }
        float c = (float)((e - s) < 1 ? 1 : (e - s));
        P[f2 * 2]     = ax / c;
        P[f2 * 2 + 1] = ay / c;
    }
    __syncthreads();
    if (t < 16) {
        float acc = bo[t];
        for (int k = 0; k < HID; ++k) acc += P[k] * Wo[k * 16 + t];
        out[g * 16 + t] = acc;
    }
}

// ---------------- launch ----------------

extern "C" void kernel_launch(void* const* d_in, const int* in_sizes, int n_in,
                              void* d_out, int out_size, void* d_ws, size_t ws_size,
                              hipStream_t stream) {
    const float* x       = (const float*)d_in[0];
    const int*   ei      = (const int*)d_in[1];
    const float* temb_in = (const float*)d_in[2];
    const int*   batch   = (const int*)d_in[3];
    const float* Wt      = (const float*)d_in[4];
    const float* bt      = (const float*)d_in[5];
    const float* W1      = (const float*)d_in[6];
    const float* b1      = (const float*)d_in[7];
    const float* Ws      = (const float*)d_in[8];
    const float* bs      = (const float*)d_in[9];
    const float* Wo      = (const float*)d_in[10];
    const float* bo      = (const float*)d_in[11];
    float* out = (float*)d_out;

    const int N = N_NODES, E = N_EDGES;
    const int* src = ei;
    const int* dst = ei + E;

    char* p = (char*)d_ws;
    auto carve = [&](size_t bytes) -> void* {
        void* r = (void*)p;
        p += (bytes + 255) & ~(size_t)255;
        return r;
    };
    int*    row_ptr    = (int*)carve((size_t)(N + 1) * 4);
    float*  dinv       = (float*)carve((size_t)N * 4);
    int*    gstart     = (int*)carve((size_t)(N_GRAPHS + 1) * 4);
    ushort* packed     = (ushort*)carve((size_t)57344 * 2);
    int*    chunk_hist = (int*)carve((size_t)NCHUNK * NB * 4);
    int*    cbase      = (int*)carve((size_t)NCHUNK * NB * 4);
    int*    bstart     = (int*)carve((size_t)(NB + 1) * 4);
    uint*   tmp        = (uint*)carve((size_t)E * 4);
    int*    edge       = (int*)carve((size_t)E * 4);
    ushort* xb         = (ushort*)carve((size_t)(N + 16) * 64 * 2);
    ushort* tembb      = (ushort*)carve((size_t)N * 128 * 2);
    uchar*  H1f8       = (uchar*)carve((size_t)(N + 16) * 128);
    ushort* H2         = (ushort*)carve((size_t)(N + 16) * 128 * 2);
    ushort* H3         = (ushort*)carve((size_t)N * 128 * 2);

    const ushort* Wtp  = packed;
    const ushort* W1p  = packed + 16384;
    const ushort* Ws0p = packed + 24576;
    const ushort* Ws1p = packed + 40960;

    const int ntiles = N / 16;            // 6250
    const int gblk   = (ntiles + 3) / 4;  // 1563

    // prep: pack W | boundaries | cvt temb
    prep_kernel<<<3740, 256, 0, stream>>>(Wt, W1, Ws, packed, batch, gstart,
                                          temb_in, tembb);

    // CSR build v2 (bucketed counting sort; no global atomics, coalesced writes)
    hist_chunks<<<NCHUNK, 256, 0, stream>>>(dst, chunk_hist);
    scan_chunks<<<1, 256, 0, stream>>>(chunk_hist, cbase, bstart, row_ptr);
    scatter_coarse<<<NCHUNK, 256, 0, stream>>>(src, dst, cbase, tmp);
    csr_fine<<<NB, 256, 0, stream>>>(tmp, bstart, row_ptr, dinv, edge, x, xb);

    // conv1 (+fused temb layer): H1f8 = dinv * (relu(agg(G0)@W1+b1) + relu(tembb@Wt+bt))
    fused_conv<64, true, false, true, true><<<gblk, 256, 0, stream>>>(
        xb, row_ptr, edge, dinv, W1p, b1, tembb, Wtp, bt, H1f8, ntiles);
    // conv2 (fp8 gather): H2 = dinv * relu(agg(H1f8)@Ws0 + bs0)
    fused_conv<128, false, true, false, true><<<gblk, 256, 0, stream>>>(
        H1f8, row_ptr, edge, dinv, Ws0p, bs, nullptr, nullptr, nullptr, H2, ntiles);
    // conv3 (no out-scale, pool consumes raw H): H3 = relu(agg(H2)@Ws1 + bs1)
    fused_conv<128, false, false, false, false><<<gblk, 256, 0, stream>>>(
        H2, row_ptr, edge, dinv, Ws1p, bs + 128, nullptr, nullptr, nullptr, H3, ntiles);

    // pool + head (fused)
    pool_out<<<N_GRAPHS, 256, 0, stream>>>(H3, gstart, Wo, bo, out);
}

// Round 5
// 372.570 us; speedup vs baseline: 1.3160x; 1.0553x over previous
//
#include <hip/hip_runtime.h>

#define N_NODES  100000
#define N_EDGES  1600000
#define N_GRAPHS 512
#define HID      128
#define NB       196        // coarse buckets of 512 nodes (dst >> 9)
#define NCHUNK   196        // edge chunks of 8192
#define CHUNK    8192

typedef unsigned int  uint;
typedef unsigned char uchar;
typedef unsigned short ushort;
typedef __attribute__((ext_vector_type(8))) short  short8;   // 8 bf16 (4 VGPRs)
typedef __attribute__((ext_vector_type(4))) float  f32x4;
typedef __attribute__((ext_vector_type(2))) float  f32x2;

__device__ inline float bflo(uint u) { return __uint_as_float(u << 16); }
__device__ inline float bfhi(uint u) { return __uint_as_float(u & 0xffff0000u); }
__device__ inline ushort f2bf(float f) {
    uint u = __float_as_uint(f);
    return (ushort)((u + 0x7fffu + ((u >> 16) & 1u)) >> 16);   // RNE
}
__device__ inline uint pk(float a, float b) {
    return (uint)f2bf(a) | ((uint)f2bf(b) << 16);
}

// weighted row accumulate; w in {0,1} masks OOB slots (norm folded into G = dinv*H)
__device__ inline void acc8_bf16(uint4 hv, float w, float* a) {
    a[0] += w * bflo(hv.x); a[1] += w * bfhi(hv.x);
    a[2] += w * bflo(hv.y); a[3] += w * bfhi(hv.y);
    a[4] += w * bflo(hv.z); a[5] += w * bfhi(hv.z);
    a[6] += w * bflo(hv.w); a[7] += w * bfhi(hv.w);
}
__device__ inline void acc8_fp8(uint2 hv, float w, float* a) {
    f32x2 p0 = __builtin_amdgcn_cvt_pk_f32_fp8((int)hv.x, false);
    f32x2 p1 = __builtin_amdgcn_cvt_pk_f32_fp8((int)hv.x, true);
    f32x2 p2 = __builtin_amdgcn_cvt_pk_f32_fp8((int)hv.y, false);
    f32x2 p3 = __builtin_amdgcn_cvt_pk_f32_fp8((int)hv.y, true);
    a[0] += w * p0.x; a[1] += w * p0.y; a[2] += w * p1.x; a[3] += w * p1.y;
    a[4] += w * p2.x; a[5] += w * p2.y; a[6] += w * p3.x; a[7] += w * p3.y;
}

// ---------------- prep: pack W | graph boundaries | cvt temb -> bf16 ----------------
// blocks: [0,224) pack, [224,615) boundary, [615,3740) temb cvt
__global__ __launch_bounds__(256)
void prep_kernel(const float* __restrict__ Wt, const float* __restrict__ W1,
                 const float* __restrict__ Ws, ushort* __restrict__ packed,
                 const int* __restrict__ batch, int* __restrict__ gstart,
                 const float* __restrict__ temb, ushort* __restrict__ tembb) {
    int b = blockIdx.x;
    int t = threadIdx.x;
    if (b < 224) {                          // pack weights into MFMA B-frag order
        int tid = b * 256 + t;
        const float* src; int p; ushort* dst;
        if (tid < 16384)      { src = Wt;         p = tid;         dst = packed; }
        else if (tid < 24576) { src = W1;         p = tid - 16384; dst = packed + 16384; }
        else if (tid < 40960) { src = Ws;         p = tid - 24576; dst = packed + 24576; }
        else                  { src = Ws + 16384; p = tid - 40960; dst = packed + 40960; }
        int j  = p & 7;
        int L  = (p >> 3) & 63;
        int cb = (p >> 9) & 7;
        int s  = p >> 12;
        int k  = s * 32 + (L >> 4) * 8 + j;
        int n  = cb * 16 + (L & 15);
        dst[p] = f2bf(src[k * 128 + n]);
    } else if (b < 615) {                   // graph boundary scan (batch sorted)
        int i = (b - 224) * 256 + t;
        if (i >= N_NODES) return;
        int bb = batch[i];
        int prev = (i == 0) ? -1 : batch[i - 1];
        for (int g = prev + 1; g <= bb; ++g) gstart[g] = i;
        if (i == N_NODES - 1) {
            for (int g = bb + 1; g <= N_GRAPHS; ++g) gstart[g] = N_NODES;
        }
    } else {                                // cvt temb (N*128 floats, 16/thread, exact)
        long i = ((long)(b - 615) * 256 + t) * 16;
#pragma unroll
        for (int k = 0; k < 4; ++k) {
            float4 f = *(const float4*)(temb + i + k * 4);
            uint2 o; o.x = pk(f.x, f.y); o.y = pk(f.z, f.w);
            *(uint2*)(tembb + i + k * 4) = o;
        }
    }
}

// ---------------- CSR build v2: 2-level bucketed counting sort ----------------

// B1: per-chunk coarse histogram (LDS only, no global atomics)
__global__ __launch_bounds__(256)
void hist_chunks(const int* __restrict__ dst, int* __restrict__ chunk_hist) {
    __shared__ int h[NB];
    int c = blockIdx.x, t = threadIdx.x;
    if (t < NB) h[t] = 0;
    __syncthreads();
    const int4* d4 = (const int4*)dst;
#pragma unroll
    for (int k = 0; k < 8; ++k) {
        int i4 = c * (CHUNK / 4) + k * 256 + t;
        if (i4 < N_EDGES / 4) {
            int4 d = d4[i4];
            atomicAdd(&h[d.x >> 9], 1);
            atomicAdd(&h[d.y >> 9], 1);
            atomicAdd(&h[d.z >> 9], 1);
            atomicAdd(&h[d.w >> 9], 1);
        }
    }
    __syncthreads();
    if (t < NB) chunk_hist[c * NB + t] = h[t];
}

// B2: single block — bucket bases + per-(chunk,bucket) bases
__global__ __launch_bounds__(256)
void scan_chunks(const int* __restrict__ chunk_hist, int* __restrict__ cbase,
                 int* __restrict__ bstart, int* __restrict__ row_ptr) {
    __shared__ int sc[256];
    int t = threadIdx.x;
    int tot = 0;
    if (t < NB)
        for (int c = 0; c < NCHUNK; ++c) tot += chunk_hist[c * NB + t];
    sc[t] = (t < NB) ? tot : 0;
    __syncthreads();
    for (int off = 1; off < 256; off <<= 1) {
        int x = (t >= off) ? sc[t - off] : 0;
        __syncthreads();
        sc[t] += x;
        __syncthreads();
    }
    int excl = sc[t] - ((t < NB) ? tot : 0);
    if (t < NB) {
        bstart[t] = excl;
        int run = excl;
        for (int c = 0; c < NCHUNK; ++c) {
            cbase[c * NB + t] = run;
            run += chunk_hist[c * NB + t];
        }
    }
    if (t == 0) { bstart[NB] = N_EDGES; row_ptr[N_NODES] = N_EDGES; }
}

// B3: per-chunk scatter into tmp — block writes contiguous runs per bucket (coalesced)
__global__ __launch_bounds__(256)
void scatter_coarse(const int* __restrict__ src, const int* __restrict__ dst,
                    const int* __restrict__ cbase, uint* __restrict__ tmp) {
    __shared__ int cur[NB];
    int c = blockIdx.x, t = threadIdx.x;
    if (t < NB) cur[t] = cbase[c * NB + t];
    __syncthreads();
    const int4* s4p = (const int4*)src;
    const int4* d4p = (const int4*)dst;
#pragma unroll
    for (int k = 0; k < 8; ++k) {
        int i4 = c * (CHUNK / 4) + k * 256 + t;
        if (i4 < N_EDGES / 4) {
            int4 s = s4p[i4];
            int4 d = d4p[i4];
            int p;
            p = atomicAdd(&cur[d.x >> 9], 1); tmp[p] = (uint)s.x | (((uint)(d.x & 511)) << 17);
            p = atomicAdd(&cur[d.y >> 9], 1); tmp[p] = (uint)s.y | (((uint)(d.y & 511)) << 17);
            p = atomicAdd(&cur[d.z >> 9], 1); tmp[p] = (uint)s.z | (((uint)(d.z & 511)) << 17);
            p = atomicAdd(&cur[d.w >> 9], 1); tmp[p] = (uint)s.w | (((uint)(d.w & 511)) << 17);
        }
    }
}

// C: one block per bucket — local hist+scan -> row_ptr/dinv, fine scatter (XCD-local
// 32KB region -> coalesced writeback), and fused xb = bf16(dinv * x)
__global__ __launch_bounds__(256)
void csr_fine(const uint* __restrict__ tmp, const int* __restrict__ bstart,
              int* __restrict__ row_ptr, float* __restrict__ dinv,
              int* __restrict__ edge, const float* __restrict__ x,
              ushort* __restrict__ xb) {
    __shared__ int   cnt[512];
    __shared__ float dvloc[512];
    __shared__ int   ps[256];
    int b = blockIdx.x, t = threadIdx.x;
    int node0 = b << 9;
    int ncnt = min(512, N_NODES - node0);
    int s = bstart[b], e = bstart[b + 1];
    cnt[t] = 0; cnt[t + 256] = 0;
    __syncthreads();
    for (int i = s + t; i < e; i += 256) atomicAdd(&cnt[tmp[i] >> 17], 1);
    __syncthreads();
    int c0 = cnt[2 * t], c1 = cnt[2 * t + 1];
    int pair = c0 + c1;
    ps[t] = pair;
    __syncthreads();
    for (int off = 1; off < 256; off <<= 1) {
        int v = (t >= off) ? ps[t - off] : 0;
        __syncthreads();
        ps[t] += v;
        __syncthreads();
    }
    int ep = ps[t] - pair;                   // exclusive pair prefix
    int p0 = s + ep, p1 = s + ep + c0;
    float dv0 = rsqrtf((float)(c0 + 1));
    float dv1 = rsqrtf((float)(c1 + 1));
    int n0 = node0 + 2 * t;
    if (2 * t < ncnt)     { row_ptr[n0]     = p0; dinv[n0]     = dv0; }
    if (2 * t + 1 < ncnt) { row_ptr[n0 + 1] = p1; dinv[n0 + 1] = dv1; }
    dvloc[2 * t] = dv0; dvloc[2 * t + 1] = dv1;
    cnt[2 * t] = p0; cnt[2 * t + 1] = p1;    // convert counts -> absolute cursors
    __syncthreads();
    for (int i = s + t; i < e; i += 256) {
        uint rec = tmp[i];
        int p = atomicAdd(&cnt[rec >> 17], 1);
        edge[p] = (int)(rec & 0x1FFFFu);
    }
    // fused: xb rows for this bucket = bf16(dinv * x)
    for (int idx = t; idx < ncnt * 16; idx += 256) {
        int row = idx >> 4, q = idx & 15;
        float4 f = ((const float4*)(x + (size_t)(node0 + row) * 64))[q];
        float d = dvloc[row];
        uint2 o; o.x = pk(f.x * d, f.y * d); o.y = pk(f.z * d, f.w * d);
        *(uint2*)(xb + (size_t)(node0 + row) * 64 + q * 4) = o;
    }
}

// ---------------- fused GCN conv ----------------
// input rows are G = dinv*H; agg_v = dinv_v * (sum_{s in N(v)} G_s + G_v)
// O = relu(agg @ W + b) [+ relu(tembb @ Wt + bt)]; SCALEOUT: store dinv*O (next layer's G)
// Phase 1: ONE LANE-GROUP PER ROW (R4: convs 114 -> 71 us). SRC8 gathers use
// unroll-8 (fp8 payload cheap in VGPRs): halves serial edge-walk iterations.
template <int K, bool TEMB, bool SRC8, bool OUT8, bool SCALEOUT>
__global__ __launch_bounds__(256)
void fused_conv(const void* __restrict__ Hv, const int* __restrict__ rp,
                const int* __restrict__ edge, const float* __restrict__ dinv,
                const ushort* __restrict__ Wp, const float* __restrict__ bias,
                const ushort* __restrict__ tembb, const ushort* __restrict__ Wtp,
                const float* __restrict__ bias_t, void* __restrict__ Ov, int ntiles) {
    constexpr int LPR  = K / 8;       // lanes per row (8 feats/lane)
    constexpr int G    = 64 / LPR;    // concurrent rows (lane groups)
    constexpr int RPG  = 16 / G;      // serial rows per group
    constexpr int U    = SRC8 ? 8 : 4;// edge-walk unroll depth
    constexpr int LROW = 136;         // LDS row stride in shorts (bf16 staging)
    __shared__ __align__(16) ushort sA[4][16 * LROW];
    const int wave = threadIdx.x >> 6;
    const int lane = threadIdx.x & 63;
    const int tile = blockIdx.x * 4 + wave;
    if (tile >= ntiles) return;       // per-wave LDS, no barriers: safe
    const int row0 = tile * 16;
    const int g  = lane / LPR;
    const int fq = lane % LPR;
    ushort* myA = sA[wave];
    const ushort* Hb = (const ushort*)Hv;
    const uchar*  H8 = (const uchar*)Hv;

    // lane-parallel preload of row_ptr[17] / dinv[16]; broadcast via shfl
    int   rpv = rp[row0 + ((lane < 17) ? lane : 16)];
    float dvv = dinv[row0 + ((lane < 16) ? lane : 15)];

    // ---- phase 1: each group gathers its own RPG rows (no cross-group reduce) ----
    for (int rr = 0; rr < RPG; ++rr) {
        int r = g * RPG + rr;
        int v = row0 + r;
        int s = __shfl(rpv, r), e = __shfl(rpv, r + 1);
        float a[8];
        // self-loop init: a = G_v
        if constexpr (!SRC8) {
            uint4 xv = *(const uint4*)(Hb + (size_t)v * K + fq * 8);
            a[0] = bflo(xv.x); a[1] = bfhi(xv.x);
            a[2] = bflo(xv.y); a[3] = bfhi(xv.y);
            a[4] = bflo(xv.z); a[5] = bfhi(xv.z);
            a[6] = bflo(xv.w); a[7] = bfhi(xv.w);
        } else {
            uint2 xv = *(const uint2*)(H8 + (size_t)v * K + fq * 8);
            f32x2 p0 = __builtin_amdgcn_cvt_pk_f32_fp8((int)xv.x, false);
            f32x2 p1 = __builtin_amdgcn_cvt_pk_f32_fp8((int)xv.x, true);
            f32x2 p2 = __builtin_amdgcn_cvt_pk_f32_fp8((int)xv.y, false);
            f32x2 p3 = __builtin_amdgcn_cvt_pk_f32_fp8((int)xv.y, true);
            a[0] = p0.x; a[1] = p0.y; a[2] = p1.x; a[3] = p1.y;
            a[4] = p2.x; a[5] = p2.y; a[6] = p3.x; a[7] = p3.y;
        }
        int iters = (e - s + U - 1) / U;  // group-uniform; U-deep unrolled walk
        int j = s;
        for (int i = 0; i < iters; ++i, j += U) {
            int sv[U]; float wv[U];
#pragma unroll
            for (int u = 0; u < U; ++u) {
                int jv = j + u;
                int jj = (jv < e) ? jv : e - 1;   // iters>0 => e>s => e-1 valid
                sv[u] = edge[jj];                 // clamped: recent, distributed row
                wv[u] = (jv < e) ? 1.0f : 0.0f;
            }
            if constexpr (!SRC8) {
                uint4 hv[U];
#pragma unroll
                for (int u = 0; u < U; ++u)
                    hv[u] = *(const uint4*)(Hb + (size_t)sv[u] * K + fq * 8);
#pragma unroll
                for (int u = 0; u < U; ++u) acc8_bf16(hv[u], wv[u], a);
            } else {
                uint2 hv[U];
#pragma unroll
                for (int u = 0; u < U; ++u)
                    hv[u] = *(const uint2*)(H8 + (size_t)sv[u] * K + fq * 8);
#pragma unroll
                for (int u = 0; u < U; ++u) acc8_fp8(hv[u], wv[u], a);
            }
        }
        float dv = __shfl(dvv, r);        // row-uniform scale
        uint4 o;
        o.x = pk(a[0] * dv, a[1] * dv); o.y = pk(a[2] * dv, a[3] * dv);
        o.z = pk(a[4] * dv, a[5] * dv); o.w = pk(a[6] * dv, a[7] * dv);
        *(uint4*)(myA + r * LROW + fq * 8) = o;
    }

    // ---- phase 2: MFMA (A from LDS, B packed from global/L2) ----
    const int m = lane & 15, q = lane >> 4;
    f32x4 acc[8];
#pragma unroll
    for (int cb = 0; cb < 8; ++cb) acc[cb] = {0.f, 0.f, 0.f, 0.f};
    constexpr int S = K / 32;
#pragma unroll
    for (int s = 0; s < S; ++s) {
        short8 av = *(const short8*)(myA + m * LROW + s * 32 + q * 8);
#pragma unroll
        for (int cb = 0; cb < 8; ++cb) {
            short8 b = *(const short8*)(Wp + (size_t)((s * 8 + cb) * 64 + lane) * 8);
            acc[cb] = __builtin_amdgcn_mfma_f32_16x16x32_bf16(av, b, acc[cb], 0, 0, 0);
        }
    }

    // ---- phase 2b (TEMB): second MFMA chain, A = prepacked bf16 temb rows ----
    f32x4 acc2[TEMB ? 8 : 1];
    if constexpr (TEMB) {
#pragma unroll
        for (int cb = 0; cb < 8; ++cb) acc2[cb] = {0.f, 0.f, 0.f, 0.f};
        const ushort* Arow = tembb + (size_t)(row0 + m) * 128 + q * 8;
#pragma unroll
        for (int s2 = 0; s2 < 4; ++s2) {
            short8 av = *(const short8*)(Arow + s2 * 32);
#pragma unroll
            for (int cb = 0; cb < 8; ++cb) {
                short8 b = *(const short8*)(Wtp + (size_t)((s2 * 8 + cb) * 64 + lane) * 8);
                acc2[cb] = __builtin_amdgcn_mfma_f32_16x16x32_bf16(av, b, acc2[cb], 0, 0, 0);
            }
        }
    }

    // ---- phase 3: epilogue into LDS, coalesced store ----
    // C/D layout: col = lane&15, row = (lane>>4)*4 + r
    float dsc[4];
    if constexpr (SCALEOUT) {
#pragma unroll
        for (int r = 0; r < 4; ++r) dsc[r] = __shfl(dvv, q * 4 + r);
    }
    if constexpr (!OUT8) {
        ushort* Ob = (ushort*)Ov;
#pragma unroll
        for (int cb = 0; cb < 8; ++cb) {
            int colc = cb * 16 + m;
            float bv = bias[colc];
            float bt2 = TEMB ? bias_t[colc] : 0.f;
#pragma unroll
            for (int r = 0; r < 4; ++r) {
                int row = q * 4 + r;
                float v = fmaxf(acc[cb][r] + bv, 0.0f);
                if (TEMB) v += fmaxf(acc2[cb][r] + bt2, 0.0f);
                if (SCALEOUT) v *= dsc[r];
                myA[row * LROW + colc] = f2bf(v);
            }
        }
#pragma unroll
        for (int i = 0; i < 4; ++i) {
            int srow = i * 4 + (lane >> 4);
            int scol = (lane & 15) * 8;
            *(short8*)(Ob + (size_t)(row0 + srow) * 128 + scol) =
                *(const short8*)(myA + srow * LROW + scol);
        }
    } else {
        uchar* st8 = (uchar*)myA;           // byte staging, row stride 136 B
        uchar* Ob = (uchar*)Ov;
#pragma unroll
        for (int cb = 0; cb < 8; ++cb) {
            int colc = cb * 16 + m;
            float bv = bias[colc];
            float bt2 = TEMB ? bias_t[colc] : 0.f;
#pragma unroll
            for (int r = 0; r < 4; ++r) {
                int row = q * 4 + r;
                float v = fmaxf(acc[cb][r] + bv, 0.0f);
                if (TEMB) v += fmaxf(acc2[cb][r] + bt2, 0.0f);
                if (SCALEOUT) v *= dsc[r];
                int enc = __builtin_amdgcn_cvt_pk_fp8_f32(v, v, 0, false);
                st8[row * 136 + colc] = (uchar)(enc & 0xff);
            }
        }
        // 16 rows * 128 B = 2048 B; 64 lanes * 8 B = 512 B/iter -> 4 iters
#pragma unroll
        for (int i = 0; i < 4; ++i) {
            int idx = i * 64 + lane;        // [0,256)
            int srow = idx >> 4;            // [0,16)
            int soff = (idx & 15) * 8;      // [0,128) step 8
            *(uint2*)(Ob + (size_t)(row0 + srow) * 128 + soff) =
                *(const uint2*)(st8 + srow * 136 + soff);
        }
    }
}

// ---------------- pooling + output head (fused) ----------------

__global__ void pool_out(const ushort* __restrict__ h, const int* __restrict__ gstart,
                         const float* __restrict__ Wo, const float* __restrict__ bo,
                         float* __restrict__ out) {
    int g = blockIdx.x;
    int t = threadIdx.x;          // 256
    int f2 = t & 63;
    int half = t >> 6;
    int s = gstart[g], e = gstart[g + 1];
    float ax = 0.f, ay = 0.f;
    for (int i = s + half; i < e; i += 4) {
        uint u = *(const uint*)(h + (size_t)i * HID + f2 * 2);
        ax += bflo(u); ay += bfhi(u);
    }
    __shared__ float red[2][256];
    __shared__ float P[128];
    red[0][t] = ax; red[1][t] = ay;
    __syncthreads();
    if (half == 0) {
        for (int k = 1; k < 4; ++k) { ax += red[0][f2 + 64 * k]; ay += red[1][f2 + 64 * k]; }
        float c = (float)((e - s) < 1 ? 1 : (e - s));
        P[f2 * 2]     = ax / c;
        P[f2 * 2 + 1] = ay / c;
    }
    __syncthreads();
    if (t < 16) {
        float acc = bo[t];
        for (int k = 0; k < HID; ++k) acc += P[k] * Wo[k * 16 + t];
        out[g * 16 + t] = acc;
    }
}

// ---------------- launch ----------------

extern "C" void kernel_launch(void* const* d_in, const int* in_sizes, int n_in,
                              void* d_out, int out_size, void* d_ws, size_t ws_size,
                              hipStream_t stream) {
    const float* x       = (const float*)d_in[0];
    const int*   ei      = (const int*)d_in[1];
    const float* temb_in = (const float*)d_in[2];
    const int*   batch   = (const int*)d_in[3];
    const float* Wt      = (const float*)d_in[4];
    const float* bt      = (const float*)d_in[5];
    const float* W1      = (const float*)d_in[6];
    const float* b1      = (const float*)d_in[7];
    const float* Ws      = (const float*)d_in[8];
    const float* bs      = (const float*)d_in[9];
    const float* Wo      = (const float*)d_in[10];
    const float* bo      = (const float*)d_in[11];
    float* out = (float*)d_out;

    const int N = N_NODES, E = N_EDGES;
    const int* src = ei;
    const int* dst = ei + E;

    char* p = (char*)d_ws;
    auto carve = [&](size_t bytes) -> void* {
        void* r = (void*)p;
        p += (bytes + 255) & ~(size_t)255;
        return r;
    };
    int*    row_ptr    = (int*)carve((size_t)(N + 1) * 4);
    float*  dinv       = (float*)carve((size_t)N * 4);
    int*    gstart     = (int*)carve((size_t)(N_GRAPHS + 1) * 4);
    ushort* packed     = (ushort*)carve((size_t)57344 * 2);
    int*    chunk_hist = (int*)carve((size_t)NCHUNK * NB * 4);
    int*    cbase      = (int*)carve((size_t)NCHUNK * NB * 4);
    int*    bstart     = (int*)carve((size_t)(NB + 1) * 4);
    uint*   tmp        = (uint*)carve((size_t)E * 4);
    int*    edge       = (int*)carve((size_t)E * 4);
    ushort* xb         = (ushort*)carve((size_t)(N + 16) * 64 * 2);
    ushort* tembb      = (ushort*)carve((size_t)N * 128 * 2);
    uchar*  H1f8       = (uchar*)carve((size_t)(N + 16) * 128);
    uchar*  H2f8       = (uchar*)carve((size_t)(N + 16) * 128);
    ushort* H3         = (ushort*)carve((size_t)N * 128 * 2);

    const ushort* Wtp  = packed;
    const ushort* W1p  = packed + 16384;
    const ushort* Ws0p = packed + 24576;
    const ushort* Ws1p = packed + 40960;

    const int ntiles = N / 16;            // 6250
    const int gblk   = (ntiles + 3) / 4;  // 1563

    // prep: pack W | boundaries | cvt temb
    prep_kernel<<<3740, 256, 0, stream>>>(Wt, W1, Ws, packed, batch, gstart,
                                          temb_in, tembb);

    // CSR build v2 (bucketed counting sort; no global atomics, coalesced writes)
    hist_chunks<<<NCHUNK, 256, 0, stream>>>(dst, chunk_hist);
    scan_chunks<<<1, 256, 0, stream>>>(chunk_hist, cbase, bstart, row_ptr);
    scatter_coarse<<<NCHUNK, 256, 0, stream>>>(src, dst, cbase, tmp);
    csr_fine<<<NB, 256, 0, stream>>>(tmp, bstart, row_ptr, dinv, edge, x, xb);

    // conv1 (+fused temb layer): H1f8 = dinv * (relu(agg(G0)@W1+b1) + relu(tembb@Wt+bt))
    fused_conv<64, true, false, true, true><<<gblk, 256, 0, stream>>>(
        xb, row_ptr, edge, dinv, W1p, b1, tembb, Wtp, bt, H1f8, ntiles);
    // conv2 (fp8 gather, fp8 out): H2f8 = dinv * relu(agg(H1f8)@Ws0 + bs0)
    fused_conv<128, false, true, true, true><<<gblk, 256, 0, stream>>>(
        H1f8, row_ptr, edge, dinv, Ws0p, bs, nullptr, nullptr, nullptr, H2f8, ntiles);
    // conv3 (fp8 gather, bf16 out for pooling): H3 = relu(agg(H2f8)@Ws1 + bs1)
    fused_conv<128, false, true, false, false><<<gblk, 256, 0, stream>>>(
        H2f8, row_ptr, edge, dinv, Ws1p, bs + 128, nullptr, nullptr, nullptr, H3, ntiles);

    // pool + head (fused)
    pool_out<<<N_GRAPHS, 256, 0, stream>>>(H3, gstart, Wo, bo, out);
}